// Round 2
// baseline (3136.978 us; speedup 1.0000x reference)
//
#include <hip/hip_runtime.h>
#include <hip/hip_bf16.h>

#define H 128
#define NFEAT 10
#define EFEAT 10
#define EPB 8

// ---- block-wide sum helpers ----
// 128-thread block = 2 waves. Reduce NV independent values simultaneously.
template<int NV>
__device__ __forceinline__ void multi_bsum(float* v, float (*red)[2]) {
    int t = threadIdx.x;
    int lane = t & 63, wave = t >> 6;
#pragma unroll
    for (int j = 0; j < NV; j++) {
        float x = v[j];
#pragma unroll
        for (int s = 32; s > 0; s >>= 1) x += __shfl_down(x, s, 64);
        if (lane == 0) red[j][wave] = x;
    }
    __syncthreads();
#pragma unroll
    for (int j = 0; j < NV; j++) v[j] = red[j][0] + red[j][1];
    __syncthreads();
}

// single-value block sum over 128 threads
__device__ __forceinline__ float bsum1(float v, float (*red)[2]) {
    float a[1] = {v};
    multi_bsum<1>(a, red);
    return a[0];
}

// ---------------- CSR build ----------------
__global__ __launch_bounds__(256) void k_degree(const int* __restrict__ col,
                                                int* __restrict__ deg, int E, int N) {
    int i = blockIdx.x * blockDim.x + threadIdx.x;
    int E2 = E + N;
    if (i < E2) {
        int d = (i < E) ? col[i] : (i - E);
        atomicAdd(&deg[d], 1);
    }
}

__global__ __launch_bounds__(1024) void k_scan(const int* __restrict__ deg,
                                               int* __restrict__ offs,
                                               int* __restrict__ cursor, int N) {
    __shared__ int ps[1024];
    int t = threadIdx.x;
    int chunk = (N + 1023) / 1024;
    int begin = t * chunk;
    int end = begin + chunk; if (end > N) end = N;
    int s = 0;
    for (int i = begin; i < end; i++) s += deg[i];
    if (begin >= N) s = 0;
    ps[t] = s;
    __syncthreads();
    for (int off = 1; off < 1024; off <<= 1) {
        int v = (t >= off) ? ps[t - off] : 0;
        __syncthreads();
        ps[t] += v;
        __syncthreads();
    }
    int run = (t == 0) ? 0 : ps[t - 1];
    if (begin < N) {
        for (int i = begin; i < end; i++) {
            offs[i] = run;
            cursor[i] = run;
            run += deg[i];
        }
    }
    if (t == 1023) offs[N] = ps[1023];
}

__global__ __launch_bounds__(256) void k_scatter(const int* __restrict__ rowp,
                                                 const int* __restrict__ colp,
                                                 int* __restrict__ cursor,
                                                 int* __restrict__ srcs, int E, int N) {
    int i = blockIdx.x * blockDim.x + threadIdx.x;
    if (i < E + N) {
        int s, d;
        if (i < E) { s = rowp[i]; d = colp[i]; }
        else       { s = i - E;  d = i - E; }
        int pos = atomicAdd(&cursor[d], 1);
        srcs[pos] = s;
    }
}

// ---------------- Node encoder: h = relu(LN(x @ ne_w + ne_b)) ----------------
__global__ __launch_bounds__(H) void k_node_enc(const float* __restrict__ x,
                                                const float* __restrict__ w,
                                                const float* __restrict__ b,
                                                const float* __restrict__ g,
                                                const float* __restrict__ beta,
                                                float* __restrict__ h) {
    int n = blockIdx.x, t = threadIdx.x;
    __shared__ float xs[NFEAT];
    __shared__ float red[1][2];
    if (t < NFEAT) xs[t] = x[(size_t)n * NFEAT + t];
    __syncthreads();
    float acc = b[t];
    for (int k = 0; k < NFEAT; k++) acc += xs[k] * w[k * H + t];
    float mean = bsum1(acc, red) * (1.0f / H);
    float dv = acc - mean;
    float var = bsum1(dv * dv, red) * (1.0f / H);
    float y = dv * rsqrtf(var + 1e-5f) * g[t] + beta[t];
    h[(size_t)n * H + t] = fmaxf(y, 0.0f);
}

// ---------------- GAT stage 1: xp = h@w ; a_s, a_d per-head scores ----------------
__global__ __launch_bounds__(H) void k_gat_xp(const float* __restrict__ h,
                                              const float* __restrict__ w,
                                              const float* __restrict__ asrc,
                                              const float* __restrict__ adst,
                                              float* __restrict__ xp,
                                              float* __restrict__ a_s,
                                              float* __restrict__ a_d,
                                              int heads, int dout) {
    int n = blockIdx.x, t = threadIdx.x;
    __shared__ float hs[H];
    __shared__ float cs[H];
    __shared__ float cd[H];
    hs[t] = h[(size_t)n * H + t];
    __syncthreads();
    float acc = 0.0f;
    for (int k = 0; k < H; k++) acc += hs[k] * w[k * H + t];
    xp[(size_t)n * H + t] = acc;
    cs[t] = acc * asrc[t];
    cd[t] = acc * adst[t];
    __syncthreads();
    if (t < heads) {
        float ss = 0.0f, sd = 0.0f;
        for (int k = 0; k < dout; k++) { ss += cs[t * dout + k]; sd += cd[t * dout + k]; }
        a_s[(size_t)n * heads + t] = ss;
        a_d[(size_t)n * heads + t] = sd;
    }
}

// ---------------- GAT stage 2: softmax-aggregate + bias + LN + relu ----------------
__global__ __launch_bounds__(H) void k_gat_agg(const float* __restrict__ xp,
                                               const float* __restrict__ a_s,
                                               const float* __restrict__ a_d,
                                               const int* __restrict__ offs,
                                               const int* __restrict__ srcs,
                                               const float* __restrict__ bias,
                                               const float* __restrict__ g,
                                               const float* __restrict__ b,
                                               float* __restrict__ hout,
                                               int heads, int dout) {
    int n = blockIdx.x, t = threadIdx.x;
    __shared__ float red[1][2];
    int head = t / dout;
    float adv = a_d[(size_t)n * heads + head];
    int s0 = offs[n], s1 = offs[n + 1];
    float acc = 0.0f, den = 0.0f;
    for (int j = s0; j < s1; j++) {
        int s = srcs[j];
        float e = a_s[(size_t)s * heads + head] + adv;
        e = (e >= 0.0f) ? e : 0.2f * e;   // leaky_relu 0.2
        float ex = expf(e);
        den += ex;
        acc += ex * xp[(size_t)s * H + t];
    }
    float v = acc / den + bias[t];
    float mean = bsum1(v, red) * (1.0f / H);
    float dv = v - mean;
    float var = bsum1(dv * dv, red) * (1.0f / H);
    float y = dv * rsqrtf(var + 1e-5f) * g[t] + b[t];
    hout[(size_t)n * H + t] = fmaxf(y, 0.0f);
}

// ---------------- Edge classifier: fused per-edge MLP, EPB edges/block ----------------
__global__ __launch_bounds__(H) void k_edge_cls(const float* __restrict__ h,
                                                const int* __restrict__ rowp,
                                                const int* __restrict__ colp,
                                                const float* __restrict__ eattr,
                                                const float* __restrict__ ee_w,
                                                const float* __restrict__ ee_b,
                                                const float* __restrict__ ee_g,
                                                const float* __restrict__ ee_beta,
                                                const float* __restrict__ gate_w,
                                                const float* __restrict__ gate_b,
                                                const float* __restrict__ c1_w,
                                                const float* __restrict__ c1_b,
                                                const float* __restrict__ cl1_g,
                                                const float* __restrict__ cl1_b,
                                                const float* __restrict__ c2_w,
                                                const float* __restrict__ c2_b,
                                                const float* __restrict__ cl2_g,
                                                const float* __restrict__ cl2_b,
                                                const float* __restrict__ c3_w,
                                                const float* __restrict__ c3_b,
                                                float* __restrict__ out, int E) {
    int t = threadIdx.x;
    int e0 = blockIdx.x * EPB;
    int ne = min(EPB, E - e0);
    __shared__ float S[EPB][H], D[EPB][H], Ef[EPB][H], Z[EPB][H];
    __shared__ float ea[EPB][EFEAT];
    __shared__ float red[EPB][2];

    for (int j = 0; j < ne; j++) {
        int r = rowp[e0 + j], c = colp[e0 + j];
        S[j][t] = h[(size_t)r * H + t];
        D[j][t] = h[(size_t)c * H + t];
    }
    if (t < ne * EFEAT) ea[t / EFEAT][t % EFEAT] = eattr[(size_t)e0 * EFEAT + t];
    __syncthreads();

    // ---- edge encoder: relu(LN(ea @ ee_w + ee_b)) ----
    {
        float wv[EFEAT];
#pragma unroll
        for (int k = 0; k < EFEAT; k++) wv[k] = ee_w[k * H + t];
        float eb = ee_b[t], eg = ee_g[t], ez = ee_beta[t];
        float v[EPB], mean[EPB], var[EPB];
#pragma unroll
        for (int j = 0; j < EPB; j++) {
            float a = eb;
#pragma unroll
            for (int k = 0; k < EFEAT; k++) a += ea[j][k] * wv[k];
            v[j] = a;
            mean[j] = a;
        }
        multi_bsum<EPB>(mean, red);
#pragma unroll
        for (int j = 0; j < EPB; j++) {
            mean[j] *= (1.0f / H);
            float dv = v[j] - mean[j];
            var[j] = dv * dv;
        }
        multi_bsum<EPB>(var, red);
#pragma unroll
        for (int j = 0; j < EPB; j++) {
            float y = (v[j] - mean[j]) * rsqrtf(var[j] * (1.0f / H) + 1e-5f) * eg + ez;
            Ef[j][t] = fmaxf(y, 0.0f);
        }
    }
    __syncthreads();

    // ---- gate = sigmoid([S,D,E] @ gate_w + gate_b); S += g*E; D += g*E ----
    {
        float ga[EPB];
        float gb = gate_b[t];
#pragma unroll
        for (int j = 0; j < EPB; j++) ga[j] = gb;
        for (int k = 0; k < H; k++) {
            float w1 = gate_w[k * H + t];
            float w2 = gate_w[(H + k) * H + t];
            float w3 = gate_w[(2 * H + k) * H + t];
#pragma unroll
            for (int j = 0; j < EPB; j++)
                ga[j] += S[j][k] * w1 + D[j][k] * w2 + Ef[j][k] * w3;
        }
        __syncthreads();   // all S,D,Ef reads complete
#pragma unroll
        for (int j = 0; j < EPB; j++) {
            float g = 1.0f / (1.0f + expf(-ga[j]));
            float e = Ef[j][t];
            S[j][t] += g * e;
            D[j][t] += g * e;
        }
    }
    __syncthreads();

    // ---- zc1 = relu(LN([S,D] @ c1_w + c1_b)) ----
    {
        float z[EPB], mean[EPB], var[EPB];
        float cb = c1_b[t];
#pragma unroll
        for (int j = 0; j < EPB; j++) z[j] = cb;
        for (int k = 0; k < H; k++) {
            float w1 = c1_w[k * H + t];
            float w2 = c1_w[(H + k) * H + t];
#pragma unroll
            for (int j = 0; j < EPB; j++)
                z[j] += S[j][k] * w1 + D[j][k] * w2;
        }
#pragma unroll
        for (int j = 0; j < EPB; j++) mean[j] = z[j];
        multi_bsum<EPB>(mean, red);
#pragma unroll
        for (int j = 0; j < EPB; j++) {
            mean[j] *= (1.0f / H);
            float dv = z[j] - mean[j];
            var[j] = dv * dv;
        }
        multi_bsum<EPB>(var, red);
        float g1 = cl1_g[t], b1 = cl1_b[t];
#pragma unroll
        for (int j = 0; j < EPB; j++) {
            float y = (z[j] - mean[j]) * rsqrtf(var[j] * (1.0f / H) + 1e-5f) * g1 + b1;
            Z[j][t] = fmaxf(y, 0.0f);
        }
    }
    __syncthreads();

    // ---- zc2 = relu(LN(Z @ c2_w + c2_b)), width 64 ----
    {
        const int HW = H / 2;
        bool act = (t < HW);
        float z[EPB], mean[EPB], var[EPB];
        float cb = act ? c2_b[t] : 0.0f;
#pragma unroll
        for (int j = 0; j < EPB; j++) z[j] = cb;
        if (act) {
            for (int k = 0; k < H; k++) {
                float w = c2_w[k * HW + t];
#pragma unroll
                for (int j = 0; j < EPB; j++) z[j] += Z[j][k] * w;
            }
        }
#pragma unroll
        for (int j = 0; j < EPB; j++) mean[j] = act ? z[j] : 0.0f;
        multi_bsum<EPB>(mean, red);
#pragma unroll
        for (int j = 0; j < EPB; j++) {
            mean[j] *= (1.0f / HW);
            float dv = act ? (z[j] - mean[j]) : 0.0f;
            var[j] = dv * dv;
        }
        multi_bsum<EPB>(var, red);
        float g2 = act ? cl2_g[t] : 0.0f;
        float b2 = act ? cl2_b[t] : 0.0f;
        if (act) {
#pragma unroll
            for (int j = 0; j < EPB; j++) {
                float y = (z[j] - mean[j]) * rsqrtf(var[j] * (1.0f / HW) + 1e-5f) * g2 + b2;
                Z[j][t] = fmaxf(y, 0.0f);
            }
        }
    }
    __syncthreads();

    // ---- out = Z[:, 0:64] @ c3_w + c3_b  (2 classes) ----
    if (t < 2 * ne) {
        int j = t >> 1, c = t & 1;
        float o = c3_b[c];
        for (int k = 0; k < H / 2; k++) o += Z[j][k] * c3_w[k * 2 + c];
        out[(size_t)(e0 + j) * 2 + c] = o;
    }
}

extern "C" void kernel_launch(void* const* d_in, const int* in_sizes, int n_in,
                              void* d_out, int out_size, void* d_ws, size_t ws_size,
                              hipStream_t stream) {
    const float* x        = (const float*)d_in[0];
    const int*   eidx     = (const int*)d_in[1];
    const float* eattr    = (const float*)d_in[2];
    const float* ne_w     = (const float*)d_in[3];
    const float* ne_b     = (const float*)d_in[4];
    const float* ne_g     = (const float*)d_in[5];
    const float* ne_beta  = (const float*)d_in[6];
    const float* ee_w     = (const float*)d_in[7];
    const float* ee_b     = (const float*)d_in[8];
    const float* ee_g     = (const float*)d_in[9];
    const float* ee_beta  = (const float*)d_in[10];
    const float* gate_w   = (const float*)d_in[11];
    const float* gate_b   = (const float*)d_in[12];
    const float* gatA_w   = (const float*)d_in[13];
    const float* gatA_as  = (const float*)d_in[14];
    const float* gatA_ad  = (const float*)d_in[15];
    const float* gatA_bias= (const float*)d_in[16];
    const float* gatB_w   = (const float*)d_in[17];
    const float* gatB_as  = (const float*)d_in[18];
    const float* gatB_ad  = (const float*)d_in[19];
    const float* gatB_bias= (const float*)d_in[20];
    const float* ln_g     = (const float*)d_in[21];
    const float* ln_b     = (const float*)d_in[22];
    const float* c1_w     = (const float*)d_in[23];
    const float* c1_b     = (const float*)d_in[24];
    const float* cl1_g    = (const float*)d_in[25];
    const float* cl1_b    = (const float*)d_in[26];
    const float* c2_w     = (const float*)d_in[27];
    const float* c2_b     = (const float*)d_in[28];
    const float* cl2_g    = (const float*)d_in[29];
    const float* cl2_b    = (const float*)d_in[30];
    const float* c3_w     = (const float*)d_in[31];
    const float* c3_b     = (const float*)d_in[32];

    const int N = in_sizes[0] / NFEAT;
    const int E = in_sizes[1] / 2;
    const int E2 = E + N;
    const int* rowp = eidx;
    const int* colp = eidx + E;

    // workspace carve-up
    char* ws = (char*)d_ws;
    size_t off = 0;
    auto alloc = [&](size_t bytes) -> void* {
        void* p = ws + off;
        off = (off + bytes + 255) & ~(size_t)255;
        return p;
    };
    float* h_a   = (float*)alloc((size_t)N * H * 4);
    float* h_b   = (float*)alloc((size_t)N * H * 4);
    float* xp    = (float*)alloc((size_t)N * H * 4);
    float* a_s   = (float*)alloc((size_t)N * 8 * 4);
    float* a_d   = (float*)alloc((size_t)N * 8 * 4);
    int*   deg   = (int*)alloc((size_t)N * 4);
    int*   cursor= (int*)alloc((size_t)N * 4);
    int*   offs  = (int*)alloc((size_t)(N + 1) * 4);
    int*   srcs  = (int*)alloc((size_t)E2 * 4);
    (void)ws_size;

    // CSR build (reused by all 3 GAT layers)
    hipMemsetAsync(deg, 0, (size_t)N * 4, stream);
    k_degree<<<(E2 + 255) / 256, 256, 0, stream>>>(colp, deg, E, N);
    k_scan<<<1, 1024, 0, stream>>>(deg, offs, cursor, N);
    k_scatter<<<(E2 + 255) / 256, 256, 0, stream>>>(rowp, colp, cursor, srcs, E, N);

    // node encoder
    k_node_enc<<<N, H, 0, stream>>>(x, ne_w, ne_b, ne_g, ne_beta, h_a);

    // GAT A layers (heads=8, dout=16, concat)
    float* hin = h_a;
    float* hout = h_b;
    for (int l = 0; l < 2; l++) {
        k_gat_xp<<<N, H, 0, stream>>>(hin, gatA_w + (size_t)l * H * H,
                                      gatA_as + l * H, gatA_ad + l * H,
                                      xp, a_s, a_d, 8, 16);
        k_gat_agg<<<N, H, 0, stream>>>(xp, a_s, a_d, offs, srcs,
                                       gatA_bias + l * H, ln_g + l * H, ln_b + l * H,
                                       hout, 8, 16);
        float* tmp = hin; hin = hout; hout = tmp;
    }
    // GAT B (heads=1, dout=128, mean over 1 head == identity)
    k_gat_xp<<<N, H, 0, stream>>>(hin, gatB_w, gatB_as, gatB_ad, xp, a_s, a_d, 1, H);
    k_gat_agg<<<N, H, 0, stream>>>(xp, a_s, a_d, offs, srcs,
                                   gatB_bias, ln_g + 2 * H, ln_b + 2 * H,
                                   hout, 1, H);

    // edge classifier (EPB edges per 128-thread block)
    k_edge_cls<<<(E + EPB - 1) / EPB, H, 0, stream>>>(hout, rowp, colp, eattr,
                                    ee_w, ee_b, ee_g, ee_beta,
                                    gate_w, gate_b,
                                    c1_w, c1_b, cl1_g, cl1_b,
                                    c2_w, c2_b, cl2_g, cl2_b,
                                    c3_w, c3_b,
                                    (float*)d_out, E);
}

// Round 3
// 1298.772 us; speedup vs baseline: 2.4153x; 2.4153x over previous
//
#include <hip/hip_runtime.h>
#include <hip/hip_bf16.h>

#define H 128
#define NFEAT 10
#define EFEAT 10
#define EPB 32   // edges per classifier block

typedef __attribute__((ext_vector_type(8))) short bf16x8;
typedef __attribute__((ext_vector_type(4))) float f32x4;

// ---- block-wide sum helpers (128-thread blocks = 2 waves) ----
__device__ __forceinline__ float bsum1(float v, float (*red)[2]) {
    int t = threadIdx.x;
    int lane = t & 63, wave = t >> 6;
    float x = v;
#pragma unroll
    for (int s = 32; s > 0; s >>= 1) x += __shfl_down(x, s, 64);
    if (lane == 0) red[0][wave] = x;
    __syncthreads();
    float r = red[0][0] + red[0][1];
    __syncthreads();
    return r;
}

// ---------------- CSR build ----------------
__global__ __launch_bounds__(256) void k_degree(const int* __restrict__ col,
                                                int* __restrict__ deg, int E, int N) {
    int i = blockIdx.x * blockDim.x + threadIdx.x;
    int E2 = E + N;
    if (i < E2) {
        int d = (i < E) ? col[i] : (i - E);
        atomicAdd(&deg[d], 1);
    }
}

__global__ __launch_bounds__(1024) void k_scan(const int* __restrict__ deg,
                                               int* __restrict__ offs,
                                               int* __restrict__ cursor, int N) {
    __shared__ int ps[1024];
    int t = threadIdx.x;
    int chunk = (N + 1023) / 1024;
    int begin = t * chunk;
    int end = begin + chunk; if (end > N) end = N;
    int s = 0;
    for (int i = begin; i < end; i++) s += deg[i];
    if (begin >= N) s = 0;
    ps[t] = s;
    __syncthreads();
    for (int off = 1; off < 1024; off <<= 1) {
        int v = (t >= off) ? ps[t - off] : 0;
        __syncthreads();
        ps[t] += v;
        __syncthreads();
    }
    int run = (t == 0) ? 0 : ps[t - 1];
    if (begin < N) {
        for (int i = begin; i < end; i++) {
            offs[i] = run;
            cursor[i] = run;
            run += deg[i];
        }
    }
    if (t == 1023) offs[N] = ps[1023];
}

__global__ __launch_bounds__(256) void k_scatter(const int* __restrict__ rowp,
                                                 const int* __restrict__ colp,
                                                 int* __restrict__ cursor,
                                                 int* __restrict__ srcs, int E, int N) {
    int i = blockIdx.x * blockDim.x + threadIdx.x;
    if (i < E + N) {
        int s, d;
        if (i < E) { s = rowp[i]; d = colp[i]; }
        else       { s = i - E;  d = i - E; }
        int pos = atomicAdd(&cursor[d], 1);
        srcs[pos] = s;
    }
}

// ---------------- Node encoder ----------------
__global__ __launch_bounds__(H) void k_node_enc(const float* __restrict__ x,
                                                const float* __restrict__ w,
                                                const float* __restrict__ b,
                                                const float* __restrict__ g,
                                                const float* __restrict__ beta,
                                                float* __restrict__ h) {
    int n = blockIdx.x, t = threadIdx.x;
    __shared__ float xs[NFEAT];
    __shared__ float red[1][2];
    if (t < NFEAT) xs[t] = x[(size_t)n * NFEAT + t];
    __syncthreads();
    float acc = b[t];
    for (int k = 0; k < NFEAT; k++) acc += xs[k] * w[k * H + t];
    float mean = bsum1(acc, red) * (1.0f / H);
    float dv = acc - mean;
    float var = bsum1(dv * dv, red) * (1.0f / H);
    float y = dv * rsqrtf(var + 1e-5f) * g[t] + beta[t];
    h[(size_t)n * H + t] = fmaxf(y, 0.0f);
}

// ---------------- GAT stage 1 ----------------
__global__ __launch_bounds__(H) void k_gat_xp(const float* __restrict__ h,
                                              const float* __restrict__ w,
                                              const float* __restrict__ asrc,
                                              const float* __restrict__ adst,
                                              float* __restrict__ xp,
                                              float* __restrict__ a_s,
                                              float* __restrict__ a_d,
                                              int heads, int dout) {
    int n = blockIdx.x, t = threadIdx.x;
    __shared__ float hs[H];
    __shared__ float cs[H];
    __shared__ float cd[H];
    hs[t] = h[(size_t)n * H + t];
    __syncthreads();
    float acc = 0.0f;
    for (int k = 0; k < H; k++) acc += hs[k] * w[k * H + t];
    xp[(size_t)n * H + t] = acc;
    cs[t] = acc * asrc[t];
    cd[t] = acc * adst[t];
    __syncthreads();
    if (t < heads) {
        float ss = 0.0f, sd = 0.0f;
        for (int k = 0; k < dout; k++) { ss += cs[t * dout + k]; sd += cd[t * dout + k]; }
        a_s[(size_t)n * heads + t] = ss;
        a_d[(size_t)n * heads + t] = sd;
    }
}

// ---------------- GAT stage 2 ----------------
__global__ __launch_bounds__(H) void k_gat_agg(const float* __restrict__ xp,
                                               const float* __restrict__ a_s,
                                               const float* __restrict__ a_d,
                                               const int* __restrict__ offs,
                                               const int* __restrict__ srcs,
                                               const float* __restrict__ bias,
                                               const float* __restrict__ g,
                                               const float* __restrict__ b,
                                               float* __restrict__ hout,
                                               int heads, int dout) {
    int n = blockIdx.x, t = threadIdx.x;
    __shared__ float red[1][2];
    int head = t / dout;
    float adv = a_d[(size_t)n * heads + head];
    int s0 = offs[n], s1 = offs[n + 1];
    float acc = 0.0f, den = 0.0f;
    for (int j = s0; j < s1; j++) {
        int s = srcs[j];
        float e = a_s[(size_t)s * heads + head] + adv;
        e = (e >= 0.0f) ? e : 0.2f * e;
        float ex = expf(e);
        den += ex;
        acc += ex * xp[(size_t)s * H + t];
    }
    float v = acc / den + bias[t];
    float mean = bsum1(v, red) * (1.0f / H);
    float dv = v - mean;
    float var = bsum1(dv * dv, red) * (1.0f / H);
    float y = dv * rsqrtf(var + 1e-5f) * g[t] + b[t];
    hout[(size_t)n * H + t] = fmaxf(y, 0.0f);
}

// ---------------- f32 -> bf16 convert ----------------
__global__ __launch_bounds__(256) void k_cvt_h(const float* __restrict__ src,
                                               __hip_bfloat16* __restrict__ dst, int n) {
    int i = blockIdx.x * blockDim.x + threadIdx.x;
    if (i < n) dst[i] = __float2bfloat16(src[i]);
}

// ---------------- weight prep: transpose + bf16 ----------------
// gate_wT[128][384], c1_wT[128][256], c2_wT[64][128]
__global__ __launch_bounds__(256) void k_wprep(const float* __restrict__ gate_w,
                                               const float* __restrict__ c1_w,
                                               const float* __restrict__ c2_w,
                                               __hip_bfloat16* __restrict__ gate_wT,
                                               __hip_bfloat16* __restrict__ c1_wT,
                                               __hip_bfloat16* __restrict__ c2_wT) {
    int i = blockIdx.x * blockDim.x + threadIdx.x;
    if (i < 49152) {                       // 128*384
        int n = i / 384, k = i % 384;
        gate_wT[i] = __float2bfloat16(gate_w[k * 128 + n]);
    } else if (i < 81920) {                // + 128*256
        int j = i - 49152;
        int n = j / 256, k = j % 256;
        c1_wT[j] = __float2bfloat16(c1_w[k * 128 + n]);
    } else if (i < 90112) {                // + 64*128
        int j = i - 81920;
        int n = j / 128, k = j % 128;
        c2_wT[j] = __float2bfloat16(c2_w[k * 64 + n]);
    }
}

// ---------------- Edge classifier: MFMA fused MLP ----------------
// 32 edges/block, 256 threads = 4 waves.
// A1 [32][392] bf16 : [S(0:128) | D(128:256) | Ef(256:384)]  stride 392 -> 196 words (=4 banks mod 32)
// WT [128][40] bf16 : staged weight chunk (N x 32k), stride 20 words
// A2 [32][264] bf16 : [S' | D'] for c1
// CF [32][132] f32  : f32 epilogue scratch
// A3 [32][136] bf16 : c1 output (LN+relu) for c2
__global__ __launch_bounds__(256, 2) void k_edge_cls_mfma(
        const __hip_bfloat16* __restrict__ h_bf,
        const int* __restrict__ rowp, const int* __restrict__ colp,
        const float* __restrict__ eattr,
        const float* __restrict__ ee_w, const float* __restrict__ ee_b,
        const float* __restrict__ ee_g, const float* __restrict__ ee_beta,
        const __hip_bfloat16* __restrict__ gate_wT, const float* __restrict__ gate_b,
        const __hip_bfloat16* __restrict__ c1_wT, const float* __restrict__ c1_b,
        const float* __restrict__ cl1_g, const float* __restrict__ cl1_b,
        const __hip_bfloat16* __restrict__ c2_wT, const float* __restrict__ c2_b,
        const float* __restrict__ cl2_g, const float* __restrict__ cl2_b,
        const float* __restrict__ c3_w, const float* __restrict__ c3_b,
        float* __restrict__ out, int E) {
    __shared__ __hip_bfloat16 A1[EPB * 392];
    __shared__ __hip_bfloat16 WT[128 * 40];
    __shared__ __hip_bfloat16 A2[EPB * 264];
    __shared__ float          CF[EPB * 132];
    __shared__ __hip_bfloat16 A3[EPB * 136];
    __shared__ float          ea[EPB][EFEAT];

    int t = threadIdx.x;
    int e0 = blockIdx.x * EPB;
    int ne = min(EPB, E - e0);

    int w = t >> 6;           // wave 0..3
    int l = t & 63;           // lane
    int ln15 = l & 15;
    int q8 = (l >> 4) * 8;    // k-offset of this lane's fragment
    int mt = w >> 1;          // M tile (0/1)
    int ng = (w & 1) * 4;     // first N tile (gate/c1)

    // ---- gather S, D rows (bf16) ----
#pragma unroll
    for (int seg = 0; seg < 2; seg++) {
        const int* idxp = seg ? colp : rowp;
#pragma unroll
        for (int rep = 0; rep < 2; rep++) {
            int idx = rep * 256 + t;          // 0..511
            int row = idx >> 4, ch = idx & 15;
            int e = min(e0 + row, E - 1);
            int node = idxp[e];
            *(uint4*)&A1[row * 392 + seg * 128 + ch * 8] =
                *(const uint4*)(h_bf + (size_t)node * 128 + ch * 8);
        }
    }
    // stage edge attrs (f32)
    for (int idx = t; idx < EPB * EFEAT; idx += 256) {
        int row = idx / EFEAT, k = idx % EFEAT;
        int e = min(e0 + row, E - 1);
        ea[row][k] = eattr[(size_t)e * EFEAT + k];
    }
    __syncthreads();

    // ---- edge encoder: Ef = relu(LN(ea @ ee_w + ee_b)) -> A1[:,256:384] ----
    {
        int row = t >> 3, cg = t & 7;        // 8 threads per row, 16 cols each
        float a[16];
        float psum = 0.0f;
#pragma unroll
        for (int i = 0; i < 16; i++) {
            int c = cg * 16 + i;
            float acc = ee_b[c];
#pragma unroll
            for (int k = 0; k < EFEAT; k++) acc += ea[row][k] * ee_w[k * 128 + c];
            a[i] = acc; psum += acc;
        }
        psum += __shfl_xor(psum, 1, 8);
        psum += __shfl_xor(psum, 2, 8);
        psum += __shfl_xor(psum, 4, 8);
        float mean = psum * (1.0f / 128.0f);
        float pvar = 0.0f;
#pragma unroll
        for (int i = 0; i < 16; i++) { float d = a[i] - mean; pvar += d * d; }
        pvar += __shfl_xor(pvar, 1, 8);
        pvar += __shfl_xor(pvar, 2, 8);
        pvar += __shfl_xor(pvar, 4, 8);
        float rstd = rsqrtf(pvar * (1.0f / 128.0f) + 1e-5f);
#pragma unroll
        for (int i = 0; i < 16; i++) {
            int c = cg * 16 + i;
            float y = (a[i] - mean) * rstd * ee_g[c] + ee_beta[c];
            A1[row * 392 + 256 + c] = __float2bfloat16(fmaxf(y, 0.0f));
        }
    }
    __syncthreads();

    // ---- GEMM1: gate = sigmoid([S|D|Ef] @ gate_w + gate_b) ; A2 = [S+g*Ef | D+g*Ef] ----
    {
        f32x4 acc[4] = {};
        for (int kk = 0; kk < 384; kk += 32) {
            {   // stage WT chunk [128 n][32 k]
                int n = t >> 1, k0 = (t & 1) * 16;
                const uint4* src = (const uint4*)(gate_wT + n * 384 + kk + k0);
                uint4 v0 = src[0], v1 = src[1];
                *(uint4*)&WT[n * 40 + k0] = v0;
                *(uint4*)&WT[n * 40 + k0 + 8] = v1;
            }
            __syncthreads();
            bf16x8 af = *(const bf16x8*)&A1[(mt * 16 + ln15) * 392 + kk + q8];
#pragma unroll
            for (int i = 0; i < 4; i++) {
                bf16x8 bfr = *(const bf16x8*)&WT[((ng + i) * 16 + ln15) * 40 + q8];
                acc[i] = __builtin_amdgcn_mfma_f32_16x16x32_bf16(af, bfr, acc[i], 0, 0, 0);
            }
            __syncthreads();
        }
#pragma unroll
        for (int i = 0; i < 4; i++) {
            int cn = (ng + i) * 16 + ln15;
            float bias = gate_b[cn];
#pragma unroll
            for (int r = 0; r < 4; r++) {
                int rr = mt * 16 + (l >> 4) * 4 + r;
                float g = 1.0f / (1.0f + expf(-(acc[i][r] + bias)));
                float ef = __bfloat162float(A1[rr * 392 + 256 + cn]);
                float s  = __bfloat162float(A1[rr * 392 + cn]);
                float d  = __bfloat162float(A1[rr * 392 + 128 + cn]);
                A2[rr * 264 + cn]       = __float2bfloat16(s + g * ef);
                A2[rr * 264 + 128 + cn] = __float2bfloat16(d + g * ef);
            }
        }
    }
    __syncthreads();

    // ---- GEMM2: z1 = relu(LN([S'|D'] @ c1_w + c1_b)) -> A3 ----
    {
        f32x4 acc[4] = {};
        for (int kk = 0; kk < 256; kk += 32) {
            {
                int n = t >> 1, k0 = (t & 1) * 16;
                const uint4* src = (const uint4*)(c1_wT + n * 256 + kk + k0);
                uint4 v0 = src[0], v1 = src[1];
                *(uint4*)&WT[n * 40 + k0] = v0;
                *(uint4*)&WT[n * 40 + k0 + 8] = v1;
            }
            __syncthreads();
            bf16x8 af = *(const bf16x8*)&A2[(mt * 16 + ln15) * 264 + kk + q8];
#pragma unroll
            for (int i = 0; i < 4; i++) {
                bf16x8 bfr = *(const bf16x8*)&WT[((ng + i) * 16 + ln15) * 40 + q8];
                acc[i] = __builtin_amdgcn_mfma_f32_16x16x32_bf16(af, bfr, acc[i], 0, 0, 0);
            }
            __syncthreads();
        }
#pragma unroll
        for (int i = 0; i < 4; i++) {
            int cn = (ng + i) * 16 + ln15;
            float bias = c1_b[cn];
#pragma unroll
            for (int r = 0; r < 4; r++) {
                int rr = mt * 16 + (l >> 4) * 4 + r;
                CF[rr * 132 + cn] = acc[i][r] + bias;
            }
        }
    }
    __syncthreads();
    {   // LN(width 128) + relu -> A3 (bf16)
        int row = t >> 3, cg = t & 7;
        float a[16];
        float psum = 0.0f;
#pragma unroll
        for (int i = 0; i < 16; i++) {
            int c = cg * 16 + i;
            a[i] = CF[row * 132 + c]; psum += a[i];
        }
        psum += __shfl_xor(psum, 1, 8);
        psum += __shfl_xor(psum, 2, 8);
        psum += __shfl_xor(psum, 4, 8);
        float mean = psum * (1.0f / 128.0f);
        float pvar = 0.0f;
#pragma unroll
        for (int i = 0; i < 16; i++) { float d = a[i] - mean; pvar += d * d; }
        pvar += __shfl_xor(pvar, 1, 8);
        pvar += __shfl_xor(pvar, 2, 8);
        pvar += __shfl_xor(pvar, 4, 8);
        float rstd = rsqrtf(pvar * (1.0f / 128.0f) + 1e-5f);
#pragma unroll
        for (int i = 0; i < 16; i++) {
            int c = cg * 16 + i;
            float y = (a[i] - mean) * rstd * cl1_g[c] + cl1_b[c];
            A3[row * 136 + c] = __float2bfloat16(fmaxf(y, 0.0f));
        }
    }
    __syncthreads();

    // ---- GEMM3: z2 = relu(LN(z1 @ c2_w + c2_b)) (width 64) -> CF f32 ----
    {
        f32x4 acc[2] = {};
        int ng3 = (w & 1) * 2;   // 4 N tiles over cols 0..63
        for (int kk = 0; kk < 128; kk += 32) {
            {   // stage [64 n][32 k]
                int n = t >> 2, k0 = (t & 3) * 8;
                *(uint4*)&WT[n * 40 + k0] = *(const uint4*)(c2_wT + n * 128 + kk + k0);
            }
            __syncthreads();
            bf16x8 af = *(const bf16x8*)&A3[(mt * 16 + ln15) * 136 + kk + q8];
#pragma unroll
            for (int i = 0; i < 2; i++) {
                bf16x8 bfr = *(const bf16x8*)&WT[((ng3 + i) * 16 + ln15) * 40 + q8];
                acc[i] = __builtin_amdgcn_mfma_f32_16x16x32_bf16(af, bfr, acc[i], 0, 0, 0);
            }
            __syncthreads();
        }
#pragma unroll
        for (int i = 0; i < 2; i++) {
            int cn = (ng3 + i) * 16 + ln15;
            float bias = c2_b[cn];
#pragma unroll
            for (int r = 0; r < 4; r++) {
                int rr = mt * 16 + (l >> 4) * 4 + r;
                CF[rr * 132 + cn] = acc[i][r] + bias;
            }
        }
    }
    __syncthreads();
    {   // LN(width 64) + relu, in place in CF
        int row = t >> 3, cg = t & 7;
        float a[8];
        float psum = 0.0f;
#pragma unroll
        for (int i = 0; i < 8; i++) {
            int c = cg * 8 + i;
            a[i] = CF[row * 132 + c]; psum += a[i];
        }
        psum += __shfl_xor(psum, 1, 8);
        psum += __shfl_xor(psum, 2, 8);
        psum += __shfl_xor(psum, 4, 8);
        float mean = psum * (1.0f / 64.0f);
        float pvar = 0.0f;
#pragma unroll
        for (int i = 0; i < 8; i++) { float d = a[i] - mean; pvar += d * d; }
        pvar += __shfl_xor(pvar, 1, 8);
        pvar += __shfl_xor(pvar, 2, 8);
        pvar += __shfl_xor(pvar, 4, 8);
        float rstd = rsqrtf(pvar * (1.0f / 64.0f) + 1e-5f);
#pragma unroll
        for (int i = 0; i < 8; i++) {
            int c = cg * 8 + i;
            float y = (a[i] - mean) * rstd * cl2_g[c] + cl2_b[c];
            CF[row * 132 + c] = fmaxf(y, 0.0f);
        }
    }
    __syncthreads();

    // ---- c3: out = z2 @ c3_w + c3_b (2 classes) ----
    if (t < 64) {
        int j = t >> 1, cls = t & 1;
        float o = c3_b[cls];
        for (int k = 0; k < 64; k++) o += CF[j * 132 + k] * c3_w[k * 2 + cls];
        if (j < ne) out[(size_t)(e0 + j) * 2 + cls] = o;
    }
}

extern "C" void kernel_launch(void* const* d_in, const int* in_sizes, int n_in,
                              void* d_out, int out_size, void* d_ws, size_t ws_size,
                              hipStream_t stream) {
    const float* x        = (const float*)d_in[0];
    const int*   eidx     = (const int*)d_in[1];
    const float* eattr    = (const float*)d_in[2];
    const float* ne_w     = (const float*)d_in[3];
    const float* ne_b     = (const float*)d_in[4];
    const float* ne_g     = (const float*)d_in[5];
    const float* ne_beta  = (const float*)d_in[6];
    const float* ee_w     = (const float*)d_in[7];
    const float* ee_b     = (const float*)d_in[8];
    const float* ee_g     = (const float*)d_in[9];
    const float* ee_beta  = (const float*)d_in[10];
    const float* gate_w   = (const float*)d_in[11];
    const float* gate_b   = (const float*)d_in[12];
    const float* gatA_w   = (const float*)d_in[13];
    const float* gatA_as  = (const float*)d_in[14];
    const float* gatA_ad  = (const float*)d_in[15];
    const float* gatA_bias= (const float*)d_in[16];
    const float* gatB_w   = (const float*)d_in[17];
    const float* gatB_as  = (const float*)d_in[18];
    const float* gatB_ad  = (const float*)d_in[19];
    const float* gatB_bias= (const float*)d_in[20];
    const float* ln_g     = (const float*)d_in[21];
    const float* ln_b     = (const float*)d_in[22];
    const float* c1_w     = (const float*)d_in[23];
    const float* c1_b     = (const float*)d_in[24];
    const float* cl1_g    = (const float*)d_in[25];
    const float* cl1_b    = (const float*)d_in[26];
    const float* c2_w     = (const float*)d_in[27];
    const float* c2_b     = (const float*)d_in[28];
    const float* cl2_g    = (const float*)d_in[29];
    const float* cl2_b    = (const float*)d_in[30];
    const float* c3_w     = (const float*)d_in[31];
    const float* c3_b     = (const float*)d_in[32];

    const int N = in_sizes[0] / NFEAT;
    const int E = in_sizes[1] / 2;
    const int E2 = E + N;
    const int* rowp = eidx;
    const int* colp = eidx + E;

    // workspace carve-up
    char* ws = (char*)d_ws;
    size_t off = 0;
    auto alloc = [&](size_t bytes) -> void* {
        void* p = ws + off;
        off = (off + bytes + 255) & ~(size_t)255;
        return p;
    };
    float* h_a   = (float*)alloc((size_t)N * H * 4);
    float* h_b   = (float*)alloc((size_t)N * H * 4);
    float* xp    = (float*)alloc((size_t)N * H * 4);
    float* a_s   = (float*)alloc((size_t)N * 8 * 4);
    float* a_d   = (float*)alloc((size_t)N * 8 * 4);
    int*   deg   = (int*)alloc((size_t)N * 4);
    int*   cursor= (int*)alloc((size_t)N * 4);
    int*   offs  = (int*)alloc((size_t)(N + 1) * 4);
    int*   srcs  = (int*)alloc((size_t)E2 * 4);
    __hip_bfloat16* h_bf    = (__hip_bfloat16*)alloc((size_t)N * H * 2);
    __hip_bfloat16* gate_wT = (__hip_bfloat16*)alloc((size_t)128 * 384 * 2);
    __hip_bfloat16* c1_wT   = (__hip_bfloat16*)alloc((size_t)128 * 256 * 2);
    __hip_bfloat16* c2_wT   = (__hip_bfloat16*)alloc((size_t)64 * 128 * 2);
    (void)ws_size;

    // weight prep (no deps)
    k_wprep<<<(90112 + 255) / 256, 256, 0, stream>>>(gate_w, c1_w, c2_w,
                                                     gate_wT, c1_wT, c2_wT);

    // CSR build (reused by all 3 GAT layers)
    hipMemsetAsync(deg, 0, (size_t)N * 4, stream);
    k_degree<<<(E2 + 255) / 256, 256, 0, stream>>>(colp, deg, E, N);
    k_scan<<<1, 1024, 0, stream>>>(deg, offs, cursor, N);
    k_scatter<<<(E2 + 255) / 256, 256, 0, stream>>>(rowp, colp, cursor, srcs, E, N);

    // node encoder
    k_node_enc<<<N, H, 0, stream>>>(x, ne_w, ne_b, ne_g, ne_beta, h_a);

    // GAT A layers (heads=8, dout=16, concat)
    float* hin = h_a;
    float* hout = h_b;
    for (int l = 0; l < 2; l++) {
        k_gat_xp<<<N, H, 0, stream>>>(hin, gatA_w + (size_t)l * H * H,
                                      gatA_as + l * H, gatA_ad + l * H,
                                      xp, a_s, a_d, 8, 16);
        k_gat_agg<<<N, H, 0, stream>>>(xp, a_s, a_d, offs, srcs,
                                       gatA_bias + l * H, ln_g + l * H, ln_b + l * H,
                                       hout, 8, 16);
        float* tmp = hin; hin = hout; hout = tmp;
    }
    // GAT B (heads=1, dout=128)
    k_gat_xp<<<N, H, 0, stream>>>(hin, gatB_w, gatB_as, gatB_ad, xp, a_s, a_d, 1, H);
    k_gat_agg<<<N, H, 0, stream>>>(xp, a_s, a_d, offs, srcs,
                                   gatB_bias, ln_g + 2 * H, ln_b + 2 * H,
                                   hout, 1, H);

    // h -> bf16
    k_cvt_h<<<((N * H) + 255) / 256, 256, 0, stream>>>(hout, h_bf, N * H);

    // fused MFMA edge classifier
    k_edge_cls_mfma<<<(E + EPB - 1) / EPB, 256, 0, stream>>>(
        h_bf, rowp, colp, eattr,
        ee_w, ee_b, ee_g, ee_beta,
        gate_wT, gate_b,
        c1_wT, c1_b, cl1_g, cl1_b,
        c2_wT, c2_b, cl2_g, cl2_b,
        c3_w, c3_b,
        (float*)d_out, E);
}

// Round 4
// 1007.288 us; speedup vs baseline: 3.1143x; 1.2894x over previous
//
#include <hip/hip_runtime.h>
#include <hip/hip_bf16.h>

#define H 128
#define NFEAT 10
#define EFEAT 10
#define EPB 32   // edges per classifier block

typedef __attribute__((ext_vector_type(8))) short bf16x8;
typedef __attribute__((ext_vector_type(4))) float f32x4;

// ---- block-wide sum (128-thread blocks = 2 waves) ----
__device__ __forceinline__ float bsum1(float v, float (*red)[2]) {
    int t = threadIdx.x;
    int lane = t & 63, wave = t >> 6;
    float x = v;
#pragma unroll
    for (int s = 32; s > 0; s >>= 1) x += __shfl_down(x, s, 64);
    if (lane == 0) red[0][wave] = x;
    __syncthreads();
    float r = red[0][0] + red[0][1];
    __syncthreads();
    return r;
}

// ---------------- CSR build ----------------
__global__ __launch_bounds__(256) void k_degree(const int* __restrict__ col,
                                                int* __restrict__ deg, int E, int N) {
    int i = blockIdx.x * blockDim.x + threadIdx.x;
    int E2 = E + N;
    if (i < E2) {
        int d = (i < E) ? col[i] : (i - E);
        atomicAdd(&deg[d], 1);
    }
}

__global__ __launch_bounds__(1024) void k_scan(const int* __restrict__ deg,
                                               int* __restrict__ offs,
                                               int* __restrict__ cursor, int N) {
    __shared__ int ps[1024];
    int t = threadIdx.x;
    int chunk = (N + 1023) / 1024;
    int begin = t * chunk;
    int end = begin + chunk; if (end > N) end = N;
    int s = 0;
    for (int i = begin; i < end; i++) s += deg[i];
    if (begin >= N) s = 0;
    ps[t] = s;
    __syncthreads();
    for (int off = 1; off < 1024; off <<= 1) {
        int v = (t >= off) ? ps[t - off] : 0;
        __syncthreads();
        ps[t] += v;
        __syncthreads();
    }
    int run = (t == 0) ? 0 : ps[t - 1];
    if (begin < N) {
        for (int i = begin; i < end; i++) {
            offs[i] = run;
            cursor[i] = run;
            run += deg[i];
        }
    }
    if (t == 1023) offs[N] = ps[1023];
}

__global__ __launch_bounds__(256) void k_scatter(const int* __restrict__ rowp,
                                                 const int* __restrict__ colp,
                                                 int* __restrict__ cursor,
                                                 int* __restrict__ srcs, int E, int N) {
    int i = blockIdx.x * blockDim.x + threadIdx.x;
    if (i < E + N) {
        int s, d;
        if (i < E) { s = rowp[i]; d = colp[i]; }
        else       { s = i - E;  d = i - E; }
        int pos = atomicAdd(&cursor[d], 1);
        srcs[pos] = s;
    }
}

// ---------------- Node encoder -> bf16 h ----------------
__global__ __launch_bounds__(H) void k_node_enc(const float* __restrict__ x,
                                                const float* __restrict__ w,
                                                const float* __restrict__ b,
                                                const float* __restrict__ g,
                                                const float* __restrict__ beta,
                                                __hip_bfloat16* __restrict__ h) {
    int n = blockIdx.x, t = threadIdx.x;
    __shared__ float xs[NFEAT];
    __shared__ float red[1][2];
    if (t < NFEAT) xs[t] = x[(size_t)n * NFEAT + t];
    __syncthreads();
    float acc = b[t];
    for (int k = 0; k < NFEAT; k++) acc += xs[k] * w[k * H + t];
    float mean = bsum1(acc, red) * (1.0f / H);
    float dv = acc - mean;
    float var = bsum1(dv * dv, red) * (1.0f / H);
    float y = dv * rsqrtf(var + 1e-5f) * g[t] + beta[t];
    h[(size_t)n * H + t] = __float2bfloat16(fmaxf(y, 0.0f));
}

// ---------------- GAT stage 1: MFMA xp = h@w, fused scores ----------------
// 64 rows/block, 256 threads (4 waves). wT: [128 n][128 k] bf16 n-major.
__global__ __launch_bounds__(256, 2) void k_gat_xp_mfma(
        const __hip_bfloat16* __restrict__ h_bf,
        const __hip_bfloat16* __restrict__ wT,
        const float* __restrict__ asrc,   // [heads*dout] flat (=128)
        const float* __restrict__ adst,
        __hip_bfloat16* __restrict__ xp_bf,
        float* __restrict__ a_s, float* __restrict__ a_d,
        int heads, int N) {
    __shared__ __hip_bfloat16 Ws[128 * 136];
    __shared__ __hip_bfloat16 As[64 * 136];
    int t = threadIdx.x;
    int n0 = blockIdx.x * 64;

    // stage W (128x128 -> padded 136 stride)
#pragma unroll
    for (int it = 0; it < 2; it++) {
        int idx = it * 256 + t;
        int row = idx >> 2, seg = idx & 3;
        const uint4* src = (const uint4*)(wT + row * 128 + seg * 32);
        uint4 v0 = src[0], v1 = src[1], v2 = src[2], v3 = src[3];
        uint4* dst = (uint4*)&Ws[row * 136 + seg * 32];
        dst[0] = v0; dst[1] = v1; dst[2] = v2; dst[3] = v3;
    }
    // stage A (64 rows)
    {
        int row = t >> 2, seg = t & 3;
        int n = n0 + row; if (n >= N) n = N - 1;
        const uint4* src = (const uint4*)(h_bf + (size_t)n * 128 + seg * 32);
        uint4 v0 = src[0], v1 = src[1], v2 = src[2], v3 = src[3];
        uint4* dst = (uint4*)&As[row * 136 + seg * 32];
        dst[0] = v0; dst[1] = v1; dst[2] = v2; dst[3] = v3;
    }
    __syncthreads();

    int w = t >> 6, l = t & 63, ln15 = l & 15, quad = l >> 4, q8 = quad * 8;
    f32x4 acc[8] = {};
#pragma unroll
    for (int k = 0; k < 128; k += 32) {
        bf16x8 af = *(const bf16x8*)&As[(w * 16 + ln15) * 136 + k + q8];
#pragma unroll
        for (int i = 0; i < 8; i++) {
            bf16x8 bfr = *(const bf16x8*)&Ws[(i * 16 + ln15) * 136 + k + q8];
            acc[i] = __builtin_amdgcn_mfma_f32_16x16x32_bf16(af, bfr, acc[i], 0, 0, 0);
        }
    }

    // ---- scores from f32 accumulators ----
    if (heads == 8) {
#pragma unroll
        for (int i = 0; i < 8; i++) {
            float av = asrc[i * 16 + ln15], dvv = adst[i * 16 + ln15];
            float ps[4], pd[4];
#pragma unroll
            for (int r = 0; r < 4; r++) { ps[r] = acc[i][r] * av; pd[r] = acc[i][r] * dvv; }
#pragma unroll
            for (int s = 1; s < 16; s <<= 1) {
#pragma unroll
                for (int r = 0; r < 4; r++) {
                    ps[r] += __shfl_xor(ps[r], s, 64);
                    pd[r] += __shfl_xor(pd[r], s, 64);
                }
            }
            if (ln15 == 0) {
#pragma unroll
                for (int r = 0; r < 4; r++) {
                    int n = n0 + w * 16 + quad * 4 + r;
                    if (n < N) { a_s[(size_t)n * 8 + i] = ps[r]; a_d[(size_t)n * 8 + i] = pd[r]; }
                }
            }
        }
    } else {
        float ps[4] = {0, 0, 0, 0}, pd[4] = {0, 0, 0, 0};
#pragma unroll
        for (int i = 0; i < 8; i++) {
            float av = asrc[i * 16 + ln15], dvv = adst[i * 16 + ln15];
#pragma unroll
            for (int r = 0; r < 4; r++) { ps[r] += acc[i][r] * av; pd[r] += acc[i][r] * dvv; }
        }
#pragma unroll
        for (int s = 1; s < 16; s <<= 1) {
#pragma unroll
            for (int r = 0; r < 4; r++) {
                ps[r] += __shfl_xor(ps[r], s, 64);
                pd[r] += __shfl_xor(pd[r], s, 64);
            }
        }
        if (ln15 == 0) {
#pragma unroll
            for (int r = 0; r < 4; r++) {
                int n = n0 + w * 16 + quad * 4 + r;
                if (n < N) { a_s[n] = ps[r]; a_d[n] = pd[r]; }
            }
        }
    }

    // ---- xp store (bf16) ----
#pragma unroll
    for (int i = 0; i < 8; i++) {
#pragma unroll
        for (int r = 0; r < 4; r++) {
            int n = n0 + w * 16 + quad * 4 + r;
            if (n < N) xp_bf[(size_t)n * 128 + i * 16 + ln15] = __float2bfloat16(acc[i][r]);
        }
    }
}

// ---------------- GAT stage 2: softmax-aggregate (bf16 gather) ----------------
__global__ __launch_bounds__(H) void k_gat_agg(const __hip_bfloat16* __restrict__ xp,
                                               const float* __restrict__ a_s,
                                               const float* __restrict__ a_d,
                                               const int* __restrict__ offs,
                                               const int* __restrict__ srcs,
                                               const float* __restrict__ bias,
                                               const float* __restrict__ g,
                                               const float* __restrict__ b,
                                               __hip_bfloat16* __restrict__ hout,
                                               int heads, int dout) {
    int n = blockIdx.x, t = threadIdx.x;
    __shared__ float red[1][2];
    int head = t / dout;
    float adv = a_d[(size_t)n * heads + head];
    int s0 = offs[n], s1 = offs[n + 1];
    float acc = 0.0f, den = 0.0f;
    for (int j = s0; j < s1; j++) {
        int s = srcs[j];
        float e = a_s[(size_t)s * heads + head] + adv;
        e = (e >= 0.0f) ? e : 0.2f * e;
        float ex = expf(e);
        den += ex;
        acc += ex * __bfloat162float(xp[(size_t)s * H + t]);
    }
    float v = acc / den + bias[t];
    float mean = bsum1(v, red) * (1.0f / H);
    float dv = v - mean;
    float var = bsum1(dv * dv, red) * (1.0f / H);
    float y = dv * rsqrtf(var + 1e-5f) * g[t] + b[t];
    hout[(size_t)n * H + t] = __float2bfloat16(fmaxf(y, 0.0f));
}

// ---------------- weight prep: transpose + bf16 ----------------
// gate_wT[128][384], c1_wT[128][256], c2_wT[64][128], wT3[3][128][128]
__global__ __launch_bounds__(256) void k_wprep(const float* __restrict__ gate_w,
                                               const float* __restrict__ c1_w,
                                               const float* __restrict__ c2_w,
                                               const float* __restrict__ gatA_w,
                                               const float* __restrict__ gatB_w,
                                               __hip_bfloat16* __restrict__ gate_wT,
                                               __hip_bfloat16* __restrict__ c1_wT,
                                               __hip_bfloat16* __restrict__ c2_wT,
                                               __hip_bfloat16* __restrict__ wT3) {
    int i = blockIdx.x * blockDim.x + threadIdx.x;
    if (i < 49152) {                       // gate 128*384
        int n = i / 384, k = i % 384;
        gate_wT[i] = __float2bfloat16(gate_w[k * 128 + n]);
    } else if (i < 81920) {                // c1 128*256
        int j = i - 49152;
        int n = j / 256, k = j % 256;
        c1_wT[j] = __float2bfloat16(c1_w[k * 128 + n]);
    } else if (i < 90112) {                // c2 64*128
        int j = i - 81920;
        int n = j / 128, k = j % 128;
        c2_wT[j] = __float2bfloat16(c2_w[k * 64 + n]);
    } else if (i < 139264) {               // gatA[0], gatA[1], gatB
        int j = i - 90112;
        int mat = j / 16384, r = j % 16384;
        int n = r / 128, k = r % 128;
        const float* src = (mat < 2) ? (gatA_w + (size_t)mat * 16384) : gatB_w;
        wT3[j] = __float2bfloat16(src[k * 128 + n]);
    }
}

// ---------------- Edge classifier: MFMA fused MLP ----------------
// 32 edges/block, 256 threads = 4 waves. K-chunk 64, CF aliased onto WT.
__global__ __launch_bounds__(256, 2) void k_edge_cls_mfma(
        const __hip_bfloat16* __restrict__ h_bf,
        const int* __restrict__ rowp, const int* __restrict__ colp,
        const float* __restrict__ eattr,
        const float* __restrict__ ee_w, const float* __restrict__ ee_b,
        const float* __restrict__ ee_g, const float* __restrict__ ee_beta,
        const __hip_bfloat16* __restrict__ gate_wT, const float* __restrict__ gate_b,
        const __hip_bfloat16* __restrict__ c1_wT, const float* __restrict__ c1_b,
        const float* __restrict__ cl1_g, const float* __restrict__ cl1_b,
        const __hip_bfloat16* __restrict__ c2_wT, const float* __restrict__ c2_b,
        const float* __restrict__ cl2_g, const float* __restrict__ cl2_b,
        const float* __restrict__ c3_w, const float* __restrict__ c3_b,
        float* __restrict__ out, int E) {
    __shared__ __hip_bfloat16 A1[EPB * 392];
    __shared__ __align__(16) unsigned char WTCF[128 * 72 * 2];  // WT bf16 [128][72] | CF f32 [32][132]
    __shared__ __hip_bfloat16 A2[EPB * 264];
    __shared__ __hip_bfloat16 A3[EPB * 136];
    __shared__ float          ea[EPB][EFEAT];
    __hip_bfloat16* WT = (__hip_bfloat16*)WTCF;
    float*          CF = (float*)WTCF;

    int t = threadIdx.x;
    int e0 = blockIdx.x * EPB;
    int ne = min(EPB, E - e0);

    int w = t >> 6;
    int l = t & 63;
    int ln15 = l & 15;
    int q8 = (l >> 4) * 8;
    int mt = w >> 1;
    int ng = (w & 1) * 4;

    // ---- gather S, D rows (bf16) ----
#pragma unroll
    for (int seg = 0; seg < 2; seg++) {
        const int* idxp = seg ? colp : rowp;
#pragma unroll
        for (int rep = 0; rep < 2; rep++) {
            int idx = rep * 256 + t;
            int row = idx >> 4, ch = idx & 15;
            int e = min(e0 + row, E - 1);
            int node = idxp[e];
            *(uint4*)&A1[row * 392 + seg * 128 + ch * 8] =
                *(const uint4*)(h_bf + (size_t)node * 128 + ch * 8);
        }
    }
    for (int idx = t; idx < EPB * EFEAT; idx += 256) {
        int row = idx / EFEAT, k = idx % EFEAT;
        int e = min(e0 + row, E - 1);
        ea[row][k] = eattr[(size_t)e * EFEAT + k];
    }
    __syncthreads();

    // ---- edge encoder -> A1[:,256:384] ----
    {
        int row = t >> 3, cg = t & 7;
        float a[16];
        float psum = 0.0f;
#pragma unroll
        for (int i = 0; i < 16; i++) {
            int c = cg * 16 + i;
            float acc = ee_b[c];
#pragma unroll
            for (int k = 0; k < EFEAT; k++) acc += ea[row][k] * ee_w[k * 128 + c];
            a[i] = acc; psum += acc;
        }
        psum += __shfl_xor(psum, 1, 8);
        psum += __shfl_xor(psum, 2, 8);
        psum += __shfl_xor(psum, 4, 8);
        float mean = psum * (1.0f / 128.0f);
        float pvar = 0.0f;
#pragma unroll
        for (int i = 0; i < 16; i++) { float d = a[i] - mean; pvar += d * d; }
        pvar += __shfl_xor(pvar, 1, 8);
        pvar += __shfl_xor(pvar, 2, 8);
        pvar += __shfl_xor(pvar, 4, 8);
        float rstd = rsqrtf(pvar * (1.0f / 128.0f) + 1e-5f);
#pragma unroll
        for (int i = 0; i < 16; i++) {
            int c = cg * 16 + i;
            float y = (a[i] - mean) * rstd * ee_g[c] + ee_beta[c];
            A1[row * 392 + 256 + c] = __float2bfloat16(fmaxf(y, 0.0f));
        }
    }
    __syncthreads();

    // ---- GEMM1: gate ----
    {
        f32x4 acc[4] = {};
        for (int kk = 0; kk < 384; kk += 64) {
            {   // stage [128 n][64 k]
                int n = t >> 1, k0 = (t & 1) * 32;
                const uint4* src = (const uint4*)(gate_wT + n * 384 + kk + k0);
                uint4 v0 = src[0], v1 = src[1], v2 = src[2], v3 = src[3];
                uint4* dst = (uint4*)&WT[n * 72 + k0];
                dst[0] = v0; dst[1] = v1; dst[2] = v2; dst[3] = v3;
            }
            __syncthreads();
#pragma unroll
            for (int ks = 0; ks < 64; ks += 32) {
                bf16x8 af = *(const bf16x8*)&A1[(mt * 16 + ln15) * 392 + kk + ks + q8];
#pragma unroll
                for (int i = 0; i < 4; i++) {
                    bf16x8 bfr = *(const bf16x8*)&WT[((ng + i) * 16 + ln15) * 72 + ks + q8];
                    acc[i] = __builtin_amdgcn_mfma_f32_16x16x32_bf16(af, bfr, acc[i], 0, 0, 0);
                }
            }
            __syncthreads();
        }
#pragma unroll
        for (int i = 0; i < 4; i++) {
            int cn = (ng + i) * 16 + ln15;
            float bias = gate_b[cn];
#pragma unroll
            for (int r = 0; r < 4; r++) {
                int rr = mt * 16 + (l >> 4) * 4 + r;
                float g = 1.0f / (1.0f + expf(-(acc[i][r] + bias)));
                float ef = __bfloat162float(A1[rr * 392 + 256 + cn]);
                float s  = __bfloat162float(A1[rr * 392 + cn]);
                float d  = __bfloat162float(A1[rr * 392 + 128 + cn]);
                A2[rr * 264 + cn]       = __float2bfloat16(s + g * ef);
                A2[rr * 264 + 128 + cn] = __float2bfloat16(d + g * ef);
            }
        }
    }
    __syncthreads();

    // ---- GEMM2: c1 ----
    {
        f32x4 acc[4] = {};
        for (int kk = 0; kk < 256; kk += 64) {
            {
                int n = t >> 1, k0 = (t & 1) * 32;
                const uint4* src = (const uint4*)(c1_wT + n * 256 + kk + k0);
                uint4 v0 = src[0], v1 = src[1], v2 = src[2], v3 = src[3];
                uint4* dst = (uint4*)&WT[n * 72 + k0];
                dst[0] = v0; dst[1] = v1; dst[2] = v2; dst[3] = v3;
            }
            __syncthreads();
#pragma unroll
            for (int ks = 0; ks < 64; ks += 32) {
                bf16x8 af = *(const bf16x8*)&A2[(mt * 16 + ln15) * 264 + kk + ks + q8];
#pragma unroll
                for (int i = 0; i < 4; i++) {
                    bf16x8 bfr = *(const bf16x8*)&WT[((ng + i) * 16 + ln15) * 72 + ks + q8];
                    acc[i] = __builtin_amdgcn_mfma_f32_16x16x32_bf16(af, bfr, acc[i], 0, 0, 0);
                }
            }
            __syncthreads();
        }
        // epilogue: CF aliases WT — all reads of WT finished (barrier above)
#pragma unroll
        for (int i = 0; i < 4; i++) {
            int cn = (ng + i) * 16 + ln15;
            float bias = c1_b[cn];
#pragma unroll
            for (int r = 0; r < 4; r++) {
                int rr = mt * 16 + (l >> 4) * 4 + r;
                CF[rr * 132 + cn] = acc[i][r] + bias;
            }
        }
    }
    __syncthreads();
    {   // LN(128) + relu -> A3
        int row = t >> 3, cg = t & 7;
        float a[16];
        float psum = 0.0f;
#pragma unroll
        for (int i = 0; i < 16; i++) {
            int c = cg * 16 + i;
            a[i] = CF[row * 132 + c]; psum += a[i];
        }
        psum += __shfl_xor(psum, 1, 8);
        psum += __shfl_xor(psum, 2, 8);
        psum += __shfl_xor(psum, 4, 8);
        float mean = psum * (1.0f / 128.0f);
        float pvar = 0.0f;
#pragma unroll
        for (int i = 0; i < 16; i++) { float d = a[i] - mean; pvar += d * d; }
        pvar += __shfl_xor(pvar, 1, 8);
        pvar += __shfl_xor(pvar, 2, 8);
        pvar += __shfl_xor(pvar, 4, 8);
        float rstd = rsqrtf(pvar * (1.0f / 128.0f) + 1e-5f);
#pragma unroll
        for (int i = 0; i < 16; i++) {
            int c = cg * 16 + i;
            float y = (a[i] - mean) * rstd * cl1_g[c] + cl1_b[c];
            A3[row * 136 + c] = __float2bfloat16(fmaxf(y, 0.0f));
        }
    }
    __syncthreads();

    // ---- GEMM3: c2 (64 wide) ----
    {
        f32x4 acc[2] = {};
        int ng3 = (w & 1) * 2;
        for (int kk = 0; kk < 128; kk += 64) {
            {   // stage [64 n][64 k]  (clobbers CF — z1 already consumed)
                int n = t >> 2, k0 = (t & 3) * 16;
                const uint4* src = (const uint4*)(c2_wT + n * 128 + kk + k0);
                uint4 v0 = src[0], v1 = src[1];
                *(uint4*)&WT[n * 72 + k0] = v0;
                *(uint4*)&WT[n * 72 + k0 + 8] = v1;
            }
            __syncthreads();
#pragma unroll
            for (int ks = 0; ks < 64; ks += 32) {
                bf16x8 af = *(const bf16x8*)&A3[(mt * 16 + ln15) * 136 + kk + ks + q8];
#pragma unroll
                for (int i = 0; i < 2; i++) {
                    bf16x8 bfr = *(const bf16x8*)&WT[((ng3 + i) * 16 + ln15) * 72 + ks + q8];
                    acc[i] = __builtin_amdgcn_mfma_f32_16x16x32_bf16(af, bfr, acc[i], 0, 0, 0);
                }
            }
            __syncthreads();
        }
#pragma unroll
        for (int i = 0; i < 2; i++) {
            int cn = (ng3 + i) * 16 + ln15;
            float bias = c2_b[cn];
#pragma unroll
            for (int r = 0; r < 4; r++) {
                int rr = mt * 16 + (l >> 4) * 4 + r;
                CF[rr * 132 + cn] = acc[i][r] + bias;
            }
        }
    }
    __syncthreads();
    {   // LN(64) + relu in CF
        int row = t >> 3, cg = t & 7;
        float a[8];
        float psum = 0.0f;
#pragma unroll
        for (int i = 0; i < 8; i++) {
            int c = cg * 8 + i;
            a[i] = CF[row * 132 + c]; psum += a[i];
        }
        psum += __shfl_xor(psum, 1, 8);
        psum += __shfl_xor(psum, 2, 8);
        psum += __shfl_xor(psum, 4, 8);
        float mean = psum * (1.0f / 64.0f);
        float pvar = 0.0f;
#pragma unroll
        for (int i = 0; i < 8; i++) { float d = a[i] - mean; pvar += d * d; }
        pvar += __shfl_xor(pvar, 1, 8);
        pvar += __shfl_xor(pvar, 2, 8);
        pvar += __shfl_xor(pvar, 4, 8);
        float rstd = rsqrtf(pvar * (1.0f / 64.0f) + 1e-5f);
#pragma unroll
        for (int i = 0; i < 8; i++) {
            int c = cg * 8 + i;
            float y = (a[i] - mean) * rstd * cl2_g[c] + cl2_b[c];
            CF[row * 132 + c] = fmaxf(y, 0.0f);
        }
    }
    __syncthreads();

    // ---- c3 ----
    if (t < 64) {
        int j = t >> 1, cls = t & 1;
        float o = c3_b[cls];
        for (int k = 0; k < 64; k++) o += CF[j * 132 + k] * c3_w[k * 2 + cls];
        if (j < ne) out[(size_t)(e0 + j) * 2 + cls] = o;
    }
}

extern "C" void kernel_launch(void* const* d_in, const int* in_sizes, int n_in,
                              void* d_out, int out_size, void* d_ws, size_t ws_size,
                              hipStream_t stream) {
    const float* x        = (const float*)d_in[0];
    const int*   eidx     = (const int*)d_in[1];
    const float* eattr    = (const float*)d_in[2];
    const float* ne_w     = (const float*)d_in[3];
    const float* ne_b     = (const float*)d_in[4];
    const float* ne_g     = (const float*)d_in[5];
    const float* ne_beta  = (const float*)d_in[6];
    const float* ee_w     = (const float*)d_in[7];
    const float* ee_b     = (const float*)d_in[8];
    const float* ee_g     = (const float*)d_in[9];
    const float* ee_beta  = (const float*)d_in[10];
    const float* gate_w   = (const float*)d_in[11];
    const float* gate_b   = (const float*)d_in[12];
    const float* gatA_w   = (const float*)d_in[13];
    const float* gatA_as  = (const float*)d_in[14];
    const float* gatA_ad  = (const float*)d_in[15];
    const float* gatA_bias= (const float*)d_in[16];
    const float* gatB_w   = (const float*)d_in[17];
    const float* gatB_as  = (const float*)d_in[18];
    const float* gatB_ad  = (const float*)d_in[19];
    const float* gatB_bias= (const float*)d_in[20];
    const float* ln_g     = (const float*)d_in[21];
    const float* ln_b     = (const float*)d_in[22];
    const float* c1_w     = (const float*)d_in[23];
    const float* c1_b     = (const float*)d_in[24];
    const float* cl1_g    = (const float*)d_in[25];
    const float* cl1_b    = (const float*)d_in[26];
    const float* c2_w     = (const float*)d_in[27];
    const float* c2_b     = (const float*)d_in[28];
    const float* cl2_g    = (const float*)d_in[29];
    const float* cl2_b    = (const float*)d_in[30];
    const float* c3_w     = (const float*)d_in[31];
    const float* c3_b     = (const float*)d_in[32];

    const int N = in_sizes[0] / NFEAT;
    const int E = in_sizes[1] / 2;
    const int E2 = E + N;
    const int* rowp = eidx;
    const int* colp = eidx + E;

    char* ws = (char*)d_ws;
    size_t off = 0;
    auto alloc = [&](size_t bytes) -> void* {
        void* p = ws + off;
        off = (off + bytes + 255) & ~(size_t)255;
        return p;
    };
    int*   deg    = (int*)alloc((size_t)N * 4);
    int*   cursor = (int*)alloc((size_t)N * 4);
    int*   offs   = (int*)alloc((size_t)(N + 1) * 4);
    int*   srcs   = (int*)alloc((size_t)E2 * 4);
    float* a_s    = (float*)alloc((size_t)N * 8 * 4);
    float* a_d    = (float*)alloc((size_t)N * 8 * 4);
    __hip_bfloat16* h_bfA  = (__hip_bfloat16*)alloc((size_t)N * H * 2);
    __hip_bfloat16* h_bfB  = (__hip_bfloat16*)alloc((size_t)N * H * 2);
    __hip_bfloat16* xp_bf  = (__hip_bfloat16*)alloc((size_t)N * H * 2);
    __hip_bfloat16* gate_wT= (__hip_bfloat16*)alloc((size_t)128 * 384 * 2);
    __hip_bfloat16* c1_wT  = (__hip_bfloat16*)alloc((size_t)128 * 256 * 2);
    __hip_bfloat16* c2_wT  = (__hip_bfloat16*)alloc((size_t)64 * 128 * 2);
    __hip_bfloat16* wT3    = (__hip_bfloat16*)alloc((size_t)3 * 128 * 128 * 2);
    (void)ws_size;

    // weight prep
    k_wprep<<<(139264 + 255) / 256, 256, 0, stream>>>(gate_w, c1_w, c2_w, gatA_w, gatB_w,
                                                      gate_wT, c1_wT, c2_wT, wT3);

    // CSR build
    hipMemsetAsync(deg, 0, (size_t)N * 4, stream);
    k_degree<<<(E2 + 255) / 256, 256, 0, stream>>>(colp, deg, E, N);
    k_scan<<<1, 1024, 0, stream>>>(deg, offs, cursor, N);
    k_scatter<<<(E2 + 255) / 256, 256, 0, stream>>>(rowp, colp, cursor, srcs, E, N);

    // node encoder -> bf16
    k_node_enc<<<N, H, 0, stream>>>(x, ne_w, ne_b, ne_g, ne_beta, h_bfA);

    int xpgrid = (N + 63) / 64;
    __hip_bfloat16* hin = h_bfA;
    __hip_bfloat16* hout = h_bfB;
    for (int l = 0; l < 2; l++) {
        k_gat_xp_mfma<<<xpgrid, 256, 0, stream>>>(hin, wT3 + (size_t)l * 16384,
                                                  gatA_as + l * H, gatA_ad + l * H,
                                                  xp_bf, a_s, a_d, 8, N);
        k_gat_agg<<<N, H, 0, stream>>>(xp_bf, a_s, a_d, offs, srcs,
                                       gatA_bias + l * H, ln_g + l * H, ln_b + l * H,
                                       hout, 8, 16);
        __hip_bfloat16* tmp = hin; hin = hout; hout = tmp;
    }
    k_gat_xp_mfma<<<xpgrid, 256, 0, stream>>>(hin, wT3 + (size_t)2 * 16384,
                                              gatB_as, gatB_ad,
                                              xp_bf, a_s, a_d, 1, N);
    k_gat_agg<<<N, H, 0, stream>>>(xp_bf, a_s, a_d, offs, srcs,
                                   gatB_bias, ln_g + 2 * H, ln_b + 2 * H,
                                   hout, 1, H);

    // fused MFMA edge classifier
    k_edge_cls_mfma<<<(E + EPB - 1) / EPB, 256, 0, stream>>>(
        hout, rowp, colp, eattr,
        ee_w, ee_b, ee_g, ee_beta,
        gate_wT, gate_b,
        c1_wT, c1_b, cl1_g, cl1_b,
        c2_wT, c2_b, cl2_g, cl2_b,
        c3_w, c3_b,
        (float*)d_out, E);
}

// Round 5
// 999.536 us; speedup vs baseline: 3.1384x; 1.0078x over previous
//
#include <hip/hip_runtime.h>
#include <hip/hip_bf16.h>

#define H 128
#define NFEAT 10
#define EFEAT 10

typedef __attribute__((ext_vector_type(8))) short bf16x8;
typedef __attribute__((ext_vector_type(4))) float f32x4;

__device__ __forceinline__ float bflo(unsigned v) { return __uint_as_float(v << 16); }
__device__ __forceinline__ float bfhi(unsigned v) { return __uint_as_float(v & 0xffff0000u); }
__device__ __forceinline__ unsigned bfpack(float a, float b) {
    __hip_bfloat16 h0 = __float2bfloat16(a), h1 = __float2bfloat16(b);
    return (unsigned)(*(unsigned short*)&h0) | ((unsigned)(*(unsigned short*)&h1) << 16);
}

// ---------------- CSR build ----------------
__global__ __launch_bounds__(256) void k_degree(const int* __restrict__ col,
                                                int* __restrict__ deg, int E, int N) {
    int i = blockIdx.x * blockDim.x + threadIdx.x;
    int E2 = E + N;
    if (i < E2) {
        int d = (i < E) ? col[i] : (i - E);
        atomicAdd(&deg[d], 1);
    }
}

__global__ __launch_bounds__(1024) void k_scan(const int* __restrict__ deg,
                                               int* __restrict__ offs,
                                               int* __restrict__ cursor, int N) {
    __shared__ int ps[1024];
    int t = threadIdx.x;
    int chunk = (N + 1023) / 1024;
    int begin = t * chunk;
    int end = begin + chunk; if (end > N) end = N;
    int s = 0;
    for (int i = begin; i < end; i++) s += deg[i];
    if (begin >= N) s = 0;
    ps[t] = s;
    __syncthreads();
    for (int off = 1; off < 1024; off <<= 1) {
        int v = (t >= off) ? ps[t - off] : 0;
        __syncthreads();
        ps[t] += v;
        __syncthreads();
    }
    int run = (t == 0) ? 0 : ps[t - 1];
    if (begin < N) {
        for (int i = begin; i < end; i++) {
            offs[i] = run;
            cursor[i] = run;
            run += deg[i];
        }
    }
    if (t == 1023) offs[N] = ps[1023];
}

__global__ __launch_bounds__(256) void k_scatter(const int* __restrict__ rowp,
                                                 const int* __restrict__ colp,
                                                 int* __restrict__ cursor,
                                                 int* __restrict__ srcs, int E, int N) {
    int i = blockIdx.x * blockDim.x + threadIdx.x;
    if (i < E + N) {
        int s, d;
        if (i < E) { s = rowp[i]; d = colp[i]; }
        else       { s = i - E;  d = i - E; }
        int pos = atomicAdd(&cursor[d], 1);
        srcs[pos] = s;
    }
}

// ---------------- Node encoder: 1 wave/node, lane = 2 features ----------------
__global__ __launch_bounds__(256) void k_node_enc(const float* __restrict__ x,
                                                  const float* __restrict__ wm,
                                                  const float* __restrict__ b,
                                                  const float* __restrict__ g,
                                                  const float* __restrict__ beta,
                                                  __hip_bfloat16* __restrict__ h, int N) {
    int t = threadIdx.x;
    int w = t >> 6, l = t & 63;
    int n = blockIdx.x * 4 + w;
    if (n >= N) return;
    float xs[NFEAT];
#pragma unroll
    for (int k = 0; k < NFEAT; k++) xs[k] = x[(size_t)n * NFEAT + k];
    float a0 = b[2 * l], a1 = b[2 * l + 1];
#pragma unroll
    for (int k = 0; k < NFEAT; k++) {
        float2 wv = *(const float2*)&wm[k * H + 2 * l];
        a0 += xs[k] * wv.x;
        a1 += xs[k] * wv.y;
    }
    float p = a0 + a1;
#pragma unroll
    for (int s = 1; s < 64; s <<= 1) p += __shfl_xor(p, s, 64);
    float mean = p * (1.0f / H);
    float d0 = a0 - mean, d1 = a1 - mean;
    float q = d0 * d0 + d1 * d1;
#pragma unroll
    for (int s = 1; s < 64; s <<= 1) q += __shfl_xor(q, s, 64);
    float rstd = rsqrtf(q * (1.0f / H) + 1e-5f);
    float y0 = fmaxf(d0 * rstd * g[2 * l] + beta[2 * l], 0.0f);
    float y1 = fmaxf(d1 * rstd * g[2 * l + 1] + beta[2 * l + 1], 0.0f);
    *(unsigned*)&h[(size_t)n * H + 2 * l] = bfpack(y0, y1);
}

// ---------------- GAT stage 1: MFMA xp = h@w, fused scores ----------------
__global__ __launch_bounds__(256, 2) void k_gat_xp_mfma(
        const __hip_bfloat16* __restrict__ h_bf,
        const __hip_bfloat16* __restrict__ wT,
        const float* __restrict__ asrc,
        const float* __restrict__ adst,
        __hip_bfloat16* __restrict__ xp_bf,
        float* __restrict__ a_s, float* __restrict__ a_d,
        int heads, int N) {
    __shared__ __hip_bfloat16 Ws[128 * 136];
    __shared__ __hip_bfloat16 As[64 * 136];
    int t = threadIdx.x;
    int n0 = blockIdx.x * 64;

#pragma unroll
    for (int it = 0; it < 2; it++) {
        int idx = it * 256 + t;
        int row = idx >> 2, seg = idx & 3;
        const uint4* src = (const uint4*)(wT + row * 128 + seg * 32);
        uint4 v0 = src[0], v1 = src[1], v2 = src[2], v3 = src[3];
        uint4* dst = (uint4*)&Ws[row * 136 + seg * 32];
        dst[0] = v0; dst[1] = v1; dst[2] = v2; dst[3] = v3;
    }
    {
        int row = t >> 2, seg = t & 3;
        int n = n0 + row; if (n >= N) n = N - 1;
        const uint4* src = (const uint4*)(h_bf + (size_t)n * 128 + seg * 32);
        uint4 v0 = src[0], v1 = src[1], v2 = src[2], v3 = src[3];
        uint4* dst = (uint4*)&As[row * 136 + seg * 32];
        dst[0] = v0; dst[1] = v1; dst[2] = v2; dst[3] = v3;
    }
    __syncthreads();

    int w = t >> 6, l = t & 63, ln15 = l & 15, quad = l >> 4, q8 = quad * 8;
    f32x4 acc[8] = {};
#pragma unroll
    for (int k = 0; k < 128; k += 32) {
        bf16x8 af = *(const bf16x8*)&As[(w * 16 + ln15) * 136 + k + q8];
#pragma unroll
        for (int i = 0; i < 8; i++) {
            bf16x8 bfr = *(const bf16x8*)&Ws[(i * 16 + ln15) * 136 + k + q8];
            acc[i] = __builtin_amdgcn_mfma_f32_16x16x32_bf16(af, bfr, acc[i], 0, 0, 0);
        }
    }

    if (heads == 8) {
#pragma unroll
        for (int i = 0; i < 8; i++) {
            float av = asrc[i * 16 + ln15], dvv = adst[i * 16 + ln15];
            float ps[4], pd[4];
#pragma unroll
            for (int r = 0; r < 4; r++) { ps[r] = acc[i][r] * av; pd[r] = acc[i][r] * dvv; }
#pragma unroll
            for (int s = 1; s < 16; s <<= 1) {
#pragma unroll
                for (int r = 0; r < 4; r++) {
                    ps[r] += __shfl_xor(ps[r], s, 64);
                    pd[r] += __shfl_xor(pd[r], s, 64);
                }
            }
            if (ln15 == 0) {
#pragma unroll
                for (int r = 0; r < 4; r++) {
                    int n = n0 + w * 16 + quad * 4 + r;
                    if (n < N) { a_s[(size_t)n * 8 + i] = ps[r]; a_d[(size_t)n * 8 + i] = pd[r]; }
                }
            }
        }
    } else {
        float ps[4] = {0, 0, 0, 0}, pd[4] = {0, 0, 0, 0};
#pragma unroll
        for (int i = 0; i < 8; i++) {
            float av = asrc[i * 16 + ln15], dvv = adst[i * 16 + ln15];
#pragma unroll
            for (int r = 0; r < 4; r++) { ps[r] += acc[i][r] * av; pd[r] += acc[i][r] * dvv; }
        }
#pragma unroll
        for (int s = 1; s < 16; s <<= 1) {
#pragma unroll
            for (int r = 0; r < 4; r++) {
                ps[r] += __shfl_xor(ps[r], s, 64);
                pd[r] += __shfl_xor(pd[r], s, 64);
            }
        }
        if (ln15 == 0) {
#pragma unroll
            for (int r = 0; r < 4; r++) {
                int n = n0 + w * 16 + quad * 4 + r;
                if (n < N) { a_s[n] = ps[r]; a_d[n] = pd[r]; }
            }
        }
    }

#pragma unroll
    for (int i = 0; i < 8; i++) {
#pragma unroll
        for (int r = 0; r < 4; r++) {
            int n = n0 + w * 16 + quad * 4 + r;
            if (n < N) xp_bf[(size_t)n * 128 + i * 16 + ln15] = __float2bfloat16(acc[i][r]);
        }
    }
}

// ---------------- GAT stage 2: 1 wave/node, lane = 2 features ----------------
__global__ __launch_bounds__(256) void k_gat_agg(const __hip_bfloat16* __restrict__ xp,
                                                 const float* __restrict__ a_s,
                                                 const float* __restrict__ a_d,
                                                 const int* __restrict__ offs,
                                                 const int* __restrict__ srcs,
                                                 const float* __restrict__ bias,
                                                 const float* __restrict__ g,
                                                 const float* __restrict__ b,
                                                 __hip_bfloat16* __restrict__ hout,
                                                 int heads, int N) {
    int t = threadIdx.x;
    int w = t >> 6, l = t & 63;
    int n = blockIdx.x * 4 + w;
    if (n >= N) return;
    int head = (heads == 8) ? (l >> 3) : 0;
    float adv = a_d[(size_t)n * heads + head];
    int s0 = offs[n], s1 = offs[n + 1];
    float acc0 = 0.0f, acc1 = 0.0f, den = 0.0f;
    for (int j = s0; j < s1; j++) {
        int s = srcs[j];
        float e = a_s[(size_t)s * heads + head] + adv;
        e = (e >= 0.0f) ? e : 0.2f * e;
        float ex = __expf(e);
        den += ex;
        unsigned v = *(const unsigned*)&xp[(size_t)s * H + 2 * l];
        acc0 += ex * bflo(v);
        acc1 += ex * bfhi(v);
    }
    float inv = 1.0f / den;
    float v0 = acc0 * inv + bias[2 * l];
    float v1 = acc1 * inv + bias[2 * l + 1];
    float p = v0 + v1;
#pragma unroll
    for (int s = 1; s < 64; s <<= 1) p += __shfl_xor(p, s, 64);
    float mean = p * (1.0f / H);
    float d0 = v0 - mean, d1 = v1 - mean;
    float q = d0 * d0 + d1 * d1;
#pragma unroll
    for (int s = 1; s < 64; s <<= 1) q += __shfl_xor(q, s, 64);
    float rstd = rsqrtf(q * (1.0f / H) + 1e-5f);
    float y0 = fmaxf(d0 * rstd * g[2 * l] + b[2 * l], 0.0f);
    float y1 = fmaxf(d1 * rstd * g[2 * l + 1] + b[2 * l + 1], 0.0f);
    *(unsigned*)&hout[(size_t)n * H + 2 * l] = bfpack(y0, y1);
}

// ---------------- weight prep: fragment-swizzled bf16 ----------------
// gate_sw [12 kc][8 nt][64 lane][8]  (K=384, N=128)
// c1_sw   [ 8 kc][8 nt][64 lane][8]  (K=256, N=128)
// c2_sw   [ 4 kc][4 nt][64 lane][8]  (K=128, N=64)
// wT3     [3][128 n][128 k] n-major  (GAT weights, LDS-staged path)
__global__ __launch_bounds__(256) void k_wprep(const float* __restrict__ gate_w,
                                               const float* __restrict__ c1_w,
                                               const float* __restrict__ c2_w,
                                               const float* __restrict__ gatA_w,
                                               const float* __restrict__ gatB_w,
                                               __hip_bfloat16* __restrict__ gate_sw,
                                               __hip_bfloat16* __restrict__ c1_sw,
                                               __hip_bfloat16* __restrict__ c2_sw,
                                               __hip_bfloat16* __restrict__ wT3) {
    int i = blockIdx.x * blockDim.x + threadIdx.x;
    if (i < 49152) {                       // gate
        int j = i & 7, lane = (i >> 3) & 63, rest = i >> 9;   // rest = kc*8+nt
        int nt = rest & 7, kc = rest >> 3;
        int n = nt * 16 + (lane & 15);
        int k = kc * 32 + (lane >> 4) * 8 + j;
        gate_sw[i] = __float2bfloat16(gate_w[k * 128 + n]);
    } else if (i < 81920) {                // c1
        int m = i - 49152;
        int j = m & 7, lane = (m >> 3) & 63, rest = m >> 9;
        int nt = rest & 7, kc = rest >> 3;
        int n = nt * 16 + (lane & 15);
        int k = kc * 32 + (lane >> 4) * 8 + j;
        c1_sw[m] = __float2bfloat16(c1_w[k * 128 + n]);
    } else if (i < 90112) {                // c2
        int m = i - 81920;
        int j = m & 7, lane = (m >> 3) & 63, rest = m >> 9;
        int nt = rest & 3, kc = rest >> 2;
        int n = nt * 16 + (lane & 15);
        int k = kc * 32 + (lane >> 4) * 8 + j;
        c2_sw[m] = __float2bfloat16(c2_w[k * 64 + n]);
    } else if (i < 139264) {               // gatA[0], gatA[1], gatB
        int m = i - 90112;
        int mat = m / 16384, r = m % 16384;
        int n = r / 128, k = r % 128;
        const float* src = (mat < 2) ? (gatA_w + (size_t)mat * 16384) : gatB_w;
        wT3[m] = __float2bfloat16(src[k * 128 + n]);
    }
}

// ---------------- Edge classifier: barrier-free MFMA MLP ----------------
// 64 edges/block, 4 waves; wave w owns edges w*16..w*16+15 and all 8 N-tiles.
// Weights: fragment-swizzled global loads (L1/L2). LN: in-wave shfl. No __syncthreads.
__global__ __launch_bounds__(256, 2) void k_edge_cls_mfma(
        const __hip_bfloat16* __restrict__ h_bf,
        const int* __restrict__ rowp, const int* __restrict__ colp,
        const float* __restrict__ eattr,
        const float* __restrict__ ee_w, const float* __restrict__ ee_b,
        const float* __restrict__ ee_g, const float* __restrict__ ee_beta,
        const __hip_bfloat16* __restrict__ gate_sw, const float* __restrict__ gate_b,
        const __hip_bfloat16* __restrict__ c1_sw, const float* __restrict__ c1_b,
        const float* __restrict__ cl1_g, const float* __restrict__ cl1_b,
        const __hip_bfloat16* __restrict__ c2_sw, const float* __restrict__ c2_b,
        const float* __restrict__ cl2_g, const float* __restrict__ cl2_b,
        const float* __restrict__ c3_w, const float* __restrict__ c3_b,
        float* __restrict__ out, int E) {
    __shared__ __hip_bfloat16 A1[64 * 392];   // [S | D | Ef] per edge, stride 392
    __shared__ __hip_bfloat16 A3[64 * 140];   // z1 (post-LN), stride 140
    int t = threadIdx.x;
    int w = t >> 6, l = t & 63;
    int ln15 = l & 15, quad = l >> 4, q8 = quad * 8;
    int e0 = blockIdx.x * 64;
    int rbase = w * 16;                       // wave-private row range

    // ---- phase 0: gather S, D (wave-private rows) ----
#pragma unroll
    for (int rep = 0; rep < 8; rep++) {
        int idx = rep * 64 + l;               // 0..511
        int seg = idx >> 8;                   // 0:S  1:D
        int rem = idx & 255;
        int r16 = rem >> 4, ch = rem & 15;
        int e = e0 + rbase + r16; if (e >= E) e = E - 1;
        int node = (seg ? colp : rowp)[e];
        *(uint4*)&A1[(rbase + r16) * 392 + seg * 128 + ch * 8] =
            *(const uint4*)(h_bf + (size_t)node * 128 + ch * 8);
    }

    // ---- phase 1: edge encoder -> A1[:,256:384]  (4 lanes/row, 32 cols/lane) ----
    {
        int r16 = l >> 2, sub = l & 3;
        int e = e0 + rbase + r16; if (e >= E) e = E - 1;
        float ea[EFEAT];
#pragma unroll
        for (int k = 0; k < EFEAT; k++) ea[k] = eattr[(size_t)e * EFEAT + k];
        float a[32];
        float psum = 0.0f;
#pragma unroll
        for (int i = 0; i < 32; i++) {
            int c = sub * 32 + i;
            float acc = ee_b[c];
#pragma unroll
            for (int k = 0; k < EFEAT; k++) acc += ea[k] * ee_w[k * 128 + c];
            a[i] = acc; psum += acc;
        }
        psum += __shfl_xor(psum, 1, 64);
        psum += __shfl_xor(psum, 2, 64);
        float mean = psum * (1.0f / 128.0f);
        float pv = 0.0f;
#pragma unroll
        for (int i = 0; i < 32; i++) { float d = a[i] - mean; pv += d * d; }
        pv += __shfl_xor(pv, 1, 64);
        pv += __shfl_xor(pv, 2, 64);
        float rstd = rsqrtf(pv * (1.0f / 128.0f) + 1e-5f);
#pragma unroll
        for (int i = 0; i < 32; i += 2) {
            int c = sub * 32 + i;
            float y0 = fmaxf((a[i] - mean) * rstd * ee_g[c] + ee_beta[c], 0.0f);
            float y1 = fmaxf((a[i + 1] - mean) * rstd * ee_g[c + 1] + ee_beta[c + 1], 0.0f);
            *(unsigned*)&A1[(rbase + r16) * 392 + 256 + c] = bfpack(y0, y1);
        }
    }

    // ---- phase 2: GEMM1 gate = sigmoid([S|D|Ef]@gate_w + b); A1 <- [S'|D'] in place ----
    {
        f32x4 acc[8] = {};
        for (int kc = 0; kc < 12; kc++) {
            bf16x8 af = *(const bf16x8*)&A1[(rbase + ln15) * 392 + kc * 32 + q8];
#pragma unroll
            for (int i = 0; i < 8; i++) {
                bf16x8 bfr = *(const bf16x8*)(gate_sw + ((size_t)(kc * 8 + i) * 64 + l) * 8);
                acc[i] = __builtin_amdgcn_mfma_f32_16x16x32_bf16(af, bfr, acc[i], 0, 0, 0);
            }
        }
#pragma unroll
        for (int i = 0; i < 8; i++) {
            int cn = i * 16 + ln15;
            float gb = gate_b[cn];
#pragma unroll
            for (int r = 0; r < 4; r++) {
                int rr = rbase + quad * 4 + r;
                float g = 1.0f / (1.0f + __expf(-(acc[i][r] + gb)));
                float ef = __bfloat162float(A1[rr * 392 + 256 + cn]);
                float s  = __bfloat162float(A1[rr * 392 + cn]);
                float d  = __bfloat162float(A1[rr * 392 + 128 + cn]);
                A1[rr * 392 + cn]       = __float2bfloat16(s + g * ef);
                A1[rr * 392 + 128 + cn] = __float2bfloat16(d + g * ef);
            }
        }
    }

    // ---- phase 3: GEMM2 z1 = relu(LN([S'|D']@c1_w + b)) -> A3 ----
    {
        f32x4 acc[8] = {};
        for (int kc = 0; kc < 8; kc++) {
            bf16x8 af = *(const bf16x8*)&A1[(rbase + ln15) * 392 + kc * 32 + q8];
#pragma unroll
            for (int i = 0; i < 8; i++) {
                bf16x8 bfr = *(const bf16x8*)(c1_sw + ((size_t)(kc * 8 + i) * 64 + l) * 8);
                acc[i] = __builtin_amdgcn_mfma_f32_16x16x32_bf16(af, bfr, acc[i], 0, 0, 0);
            }
        }
#pragma unroll
        for (int i = 0; i < 8; i++) {
            float cb = c1_b[i * 16 + ln15];
#pragma unroll
            for (int r = 0; r < 4; r++) acc[i][r] += cb;
        }
        float mean[4], rstd[4];
#pragma unroll
        for (int r = 0; r < 4; r++) {
            float p = 0.0f;
#pragma unroll
            for (int i = 0; i < 8; i++) p += acc[i][r];
            p += __shfl_xor(p, 1, 64);
            p += __shfl_xor(p, 2, 64);
            p += __shfl_xor(p, 4, 64);
            p += __shfl_xor(p, 8, 64);
            mean[r] = p * (1.0f / 128.0f);
        }
#pragma unroll
        for (int r = 0; r < 4; r++) {
            float q = 0.0f;
#pragma unroll
            for (int i = 0; i < 8; i++) { float d = acc[i][r] - mean[r]; q += d * d; }
            q += __shfl_xor(q, 1, 64);
            q += __shfl_xor(q, 2, 64);
            q += __shfl_xor(q, 4, 64);
            q += __shfl_xor(q, 8, 64);
            rstd[r] = rsqrtf(q * (1.0f / 128.0f) + 1e-5f);
        }
#pragma unroll
        for (int i = 0; i < 8; i++) {
            int cn = i * 16 + ln15;
            float g1 = cl1_g[cn], b1 = cl1_b[cn];
#pragma unroll
            for (int r = 0; r < 4; r++) {
                int rr = rbase + quad * 4 + r;
                float y = fmaxf((acc[i][r] - mean[r]) * rstd[r] * g1 + b1, 0.0f);
                A3[rr * 140 + cn] = __float2bfloat16(y);
            }
        }
    }

    // ---- phase 4: GEMM3 z2 = relu(LN(z1@c2_w + b)); out = z2@c3_w + c3_b ----
    {
        f32x4 acc[4] = {};
        for (int kc = 0; kc < 4; kc++) {
            bf16x8 af = *(const bf16x8*)&A3[(rbase + ln15) * 140 + kc * 32 + q8];
#pragma unroll
            for (int i = 0; i < 4; i++) {
                bf16x8 bfr = *(const bf16x8*)(c2_sw + ((size_t)(kc * 4 + i) * 64 + l) * 8);
                acc[i] = __builtin_amdgcn_mfma_f32_16x16x32_bf16(af, bfr, acc[i], 0, 0, 0);
            }
        }
#pragma unroll
        for (int i = 0; i < 4; i++) {
            float cb = c2_b[i * 16 + ln15];
#pragma unroll
            for (int r = 0; r < 4; r++) acc[i][r] += cb;
        }
        float mean[4], rstd[4];
#pragma unroll
        for (int r = 0; r < 4; r++) {
            float p = 0.0f;
#pragma unroll
            for (int i = 0; i < 4; i++) p += acc[i][r];
            p += __shfl_xor(p, 1, 64);
            p += __shfl_xor(p, 2, 64);
            p += __shfl_xor(p, 4, 64);
            p += __shfl_xor(p, 8, 64);
            mean[r] = p * (1.0f / 64.0f);
        }
#pragma unroll
        for (int r = 0; r < 4; r++) {
            float q = 0.0f;
#pragma unroll
            for (int i = 0; i < 4; i++) { float d = acc[i][r] - mean[r]; q += d * d; }
            q += __shfl_xor(q, 1, 64);
            q += __shfl_xor(q, 2, 64);
            q += __shfl_xor(q, 4, 64);
            q += __shfl_xor(q, 8, 64);
            rstd[r] = rsqrtf(q * (1.0f / 64.0f) + 1e-5f);
        }
        float w0[4], w1[4];
#pragma unroll
        for (int i = 0; i < 4; i++) {
            float2 cw = *(const float2*)&c3_w[(i * 16 + ln15) * 2];
            w0[i] = cw.x; w1[i] = cw.y;
        }
        float o0[4], o1[4];
#pragma unroll
        for (int r = 0; r < 4; r++) {
            float s0 = 0.0f, s1 = 0.0f;
#pragma unroll
            for (int i = 0; i < 4; i++) {
                int cn = i * 16 + ln15;
                float y = fmaxf((acc[i][r] - mean[r]) * rstd[r] * cl2_g[cn] + cl2_b[cn], 0.0f);
                s0 += y * w0[i];
                s1 += y * w1[i];
            }
            s0 += __shfl_xor(s0, 1, 64);
            s0 += __shfl_xor(s0, 2, 64);
            s0 += __shfl_xor(s0, 4, 64);
            s0 += __shfl_xor(s0, 8, 64);
            s1 += __shfl_xor(s1, 1, 64);
            s1 += __shfl_xor(s1, 2, 64);
            s1 += __shfl_xor(s1, 4, 64);
            s1 += __shfl_xor(s1, 8, 64);
            o0[r] = s0; o1[r] = s1;
        }
        if (ln15 == 0) {
            float b0 = c3_b[0], b1 = c3_b[1];
#pragma unroll
            for (int r = 0; r < 4; r++) {
                int e = e0 + rbase + quad * 4 + r;
                if (e < E) {
                    float2 o; o.x = o0[r] + b0; o.y = o1[r] + b1;
                    *(float2*)&out[(size_t)e * 2] = o;
                }
            }
        }
    }
}

extern "C" void kernel_launch(void* const* d_in, const int* in_sizes, int n_in,
                              void* d_out, int out_size, void* d_ws, size_t ws_size,
                              hipStream_t stream) {
    const float* x        = (const float*)d_in[0];
    const int*   eidx     = (const int*)d_in[1];
    const float* eattr    = (const float*)d_in[2];
    const float* ne_w     = (const float*)d_in[3];
    const float* ne_b     = (const float*)d_in[4];
    const float* ne_g     = (const float*)d_in[5];
    const float* ne_beta  = (const float*)d_in[6];
    const float* ee_w     = (const float*)d_in[7];
    const float* ee_b     = (const float*)d_in[8];
    const float* ee_g     = (const float*)d_in[9];
    const float* ee_beta  = (const float*)d_in[10];
    const float* gate_w   = (const float*)d_in[11];
    const float* gate_b   = (const float*)d_in[12];
    const float* gatA_w   = (const float*)d_in[13];
    const float* gatA_as  = (const float*)d_in[14];
    const float* gatA_ad  = (const float*)d_in[15];
    const float* gatA_bias= (const float*)d_in[16];
    const float* gatB_w   = (const float*)d_in[17];
    const float* gatB_as  = (const float*)d_in[18];
    const float* gatB_ad  = (const float*)d_in[19];
    const float* gatB_bias= (const float*)d_in[20];
    const float* ln_g     = (const float*)d_in[21];
    const float* ln_b     = (const float*)d_in[22];
    const float* c1_w     = (const float*)d_in[23];
    const float* c1_b     = (const float*)d_in[24];
    const float* cl1_g    = (const float*)d_in[25];
    const float* cl1_b    = (const float*)d_in[26];
    const float* c2_w     = (const float*)d_in[27];
    const float* c2_b     = (const float*)d_in[28];
    const float* cl2_g    = (const float*)d_in[29];
    const float* cl2_b    = (const float*)d_in[30];
    const float* c3_w     = (const float*)d_in[31];
    const float* c3_b     = (const float*)d_in[32];

    const int N = in_sizes[0] / NFEAT;
    const int E = in_sizes[1] / 2;
    const int E2 = E + N;
    const int* rowp = eidx;
    const int* colp = eidx + E;

    char* ws = (char*)d_ws;
    size_t off = 0;
    auto alloc = [&](size_t bytes) -> void* {
        void* p = ws + off;
        off = (off + bytes + 255) & ~(size_t)255;
        return p;
    };
    int*   deg    = (int*)alloc((size_t)N * 4);
    int*   cursor = (int*)alloc((size_t)N * 4);
    int*   offs   = (int*)alloc((size_t)(N + 1) * 4);
    int*   srcs   = (int*)alloc((size_t)E2 * 4);
    float* a_s    = (float*)alloc((size_t)N * 8 * 4);
    float* a_d    = (float*)alloc((size_t)N * 8 * 4);
    __hip_bfloat16* h_bfA  = (__hip_bfloat16*)alloc((size_t)N * H * 2);
    __hip_bfloat16* h_bfB  = (__hip_bfloat16*)alloc((size_t)N * H * 2);
    __hip_bfloat16* xp_bf  = (__hip_bfloat16*)alloc((size_t)N * H * 2);
    __hip_bfloat16* gate_sw= (__hip_bfloat16*)alloc((size_t)49152 * 2);
    __hip_bfloat16* c1_sw  = (__hip_bfloat16*)alloc((size_t)32768 * 2);
    __hip_bfloat16* c2_sw  = (__hip_bfloat16*)alloc((size_t)8192 * 2);
    __hip_bfloat16* wT3    = (__hip_bfloat16*)alloc((size_t)3 * 128 * 128 * 2);
    (void)ws_size;

    // weight prep
    k_wprep<<<(139264 + 255) / 256, 256, 0, stream>>>(gate_w, c1_w, c2_w, gatA_w, gatB_w,
                                                      gate_sw, c1_sw, c2_sw, wT3);

    // CSR build
    hipMemsetAsync(deg, 0, (size_t)N * 4, stream);
    k_degree<<<(E2 + 255) / 256, 256, 0, stream>>>(colp, deg, E, N);
    k_scan<<<1, 1024, 0, stream>>>(deg, offs, cursor, N);
    k_scatter<<<(E2 + 255) / 256, 256, 0, stream>>>(rowp, colp, cursor, srcs, E, N);

    // node encoder -> bf16
    int ngrid = (N + 3) / 4;
    k_node_enc<<<ngrid, 256, 0, stream>>>(x, ne_w, ne_b, ne_g, ne_beta, h_bfA, N);

    int xpgrid = (N + 63) / 64;
    __hip_bfloat16* hin = h_bfA;
    __hip_bfloat16* hout = h_bfB;
    for (int l = 0; l < 2; l++) {
        k_gat_xp_mfma<<<xpgrid, 256, 0, stream>>>(hin, wT3 + (size_t)l * 16384,
                                                  gatA_as + l * H, gatA_ad + l * H,
                                                  xp_bf, a_s, a_d, 8, N);
        k_gat_agg<<<ngrid, 256, 0, stream>>>(xp_bf, a_s, a_d, offs, srcs,
                                             gatA_bias + l * H, ln_g + l * H, ln_b + l * H,
                                             hout, 8, N);
        __hip_bfloat16* tmp = hin; hin = hout; hout = tmp;
    }
    k_gat_xp_mfma<<<xpgrid, 256, 0, stream>>>(hin, wT3 + (size_t)2 * 16384,
                                              gatB_as, gatB_ad,
                                              xp_bf, a_s, a_d, 1, N);
    k_gat_agg<<<ngrid, 256, 0, stream>>>(xp_bf, a_s, a_d, offs, srcs,
                                         gatB_bias, ln_g + 2 * H, ln_b + 2 * H,
                                         hout, 1, N);

    // barrier-free MFMA edge classifier
    k_edge_cls_mfma<<<(E + 63) / 64, 256, 0, stream>>>(
        hout, rowp, colp, eattr,
        ee_w, ee_b, ee_g, ee_beta,
        gate_sw, gate_b,
        c1_sw, c1_b, cl1_g, cl1_b,
        c2_sw, c2_b, cl2_g, cl2_b,
        c3_w, c3_b,
        (float*)d_out, E);
}